// Round 2
// baseline (2961.580 us; speedup 1.0000x reference)
//
#include <hip/hip_runtime.h>

// Problem constants (fixed by the reference)
#define NNODES 100000
#define NEDGES 1600000
// IN=64, OUT=64, ED=8, H1=64, H2=32
#define NEG_SLOPE 0.01f

// ---------------------------------------------------------------------------
// Kernel P: fold W_edge/b_edge into W1's last 64 columns.
//   w1cp[o][j] = sum_t W1[o][128+t] * W_edge[t][j]      (64 x 8)
//   b1p[o]    = b1[o] + sum_t W1[o][128+t] * b_edge[t]  (64)
// ---------------------------------------------------------------------------
__global__ void egat_precompute(const float* __restrict__ W1,
                                const float* __restrict__ b1,
                                const float* __restrict__ We,
                                const float* __restrict__ be,
                                float* __restrict__ w1cp,
                                float* __restrict__ b1p) {
    int tid = threadIdx.x;
    for (int idx = tid; idx < 512; idx += 256) {
        int o = idx >> 3, j = idx & 7;
        float s = 0.f;
        for (int t = 0; t < 64; ++t)
            s += W1[o * 192 + 128 + t] * We[t * 8 + j];
        w1cp[idx] = s;
    }
    if (tid < 64) {
        float s = b1[tid];
        for (int t = 0; t < 64; ++t)
            s += W1[tid * 192 + 128 + t] * be[t];
        b1p[tid] = s;
    }
}

// ---------------------------------------------------------------------------
// Kernel N: x_source = x@W_src^T + b_src, x_target = x@W_tgt^T + b_tgt.
// Writes x_source, x_target to workspace and d_out = x_target.
// Block = 256 threads = 4 waves; each wave handles one node per iteration.
// Both weight matrices staged transposed+interleaved in LDS: Wb[k][o] = {src,tgt}.
// ---------------------------------------------------------------------------
__global__ __launch_bounds__(256) void egat_node(
        const float* __restrict__ x,
        const float* __restrict__ Ws, const float* __restrict__ bs,
        const float* __restrict__ Wt, const float* __restrict__ bt,
        float* __restrict__ xsrc, float* __restrict__ xtgt,
        float* __restrict__ out) {
    __shared__ float2 Wb[64 * 64];      // 32 KiB
    __shared__ float  xrow[4][64];      // 1 KiB
    int tid = threadIdx.x;
    for (int idx = tid; idx < 4096; idx += 256) {
        int o = idx >> 6, k = idx & 63;
        Wb[k * 64 + o] = make_float2(Ws[idx], Wt[idx]);
    }
    __syncthreads();

    int w = tid >> 6, lane = tid & 63;
    float bsv = bs[lane], btv = bt[lane];

    for (int base = blockIdx.x * 4; base < NNODES; base += gridDim.x * 4) {
        int node = base + w;
        float xv = (node < NNODES) ? x[node * 64 + lane] : 0.f;
        xrow[w][lane] = xv;
        __syncthreads();

        float accs = bsv, acct = btv;
        #pragma unroll 8
        for (int k = 0; k < 64; ++k) {
            float xk = xrow[w][k];            // LDS broadcast
            float2 wv = Wb[k * 64 + lane];    // ~4-way conflict, cheap
            accs += xk * wv.x;
            acct += xk * wv.y;
        }
        if (node < NNODES) {
            xsrc[node * 64 + lane] = accs;
            xtgt[node * 64 + lane] = acct;
            out[node * 64 + lane]  = acct;
        }
        __syncthreads();
    }
}

// ---------------------------------------------------------------------------
// Kernel E: one thread per edge. Full attention MLP in registers.
// All weight reads are wave-uniform -> scalar loads (s_load), VALU does FMAs.
// Scatter: relu-gated f32 atomics into out[tgt].
// NOTE: harness converts int64 inputs to int32 -> edge_index is const int*.
// ---------------------------------------------------------------------------
__global__ __launch_bounds__(256) void egat_edge(
        const int* __restrict__ ei,           // [2, E] (int32)
        const float* __restrict__ eattr,      // [E, 8]
        const float* __restrict__ xsrc,       // [N, 64]
        const float* __restrict__ xtgt,       // [N, 64]
        const float* __restrict__ W1,         // [64, 192]
        const float* __restrict__ w1cp,       // [64, 8]
        const float* __restrict__ b1p,        // [64]
        const float* __restrict__ W2,         // [32, 64]
        const float* __restrict__ b2,         // [32]
        const float* __restrict__ W3,         // [1, 32]
        const float* __restrict__ b3,         // [1]
        float* __restrict__ out) {
    int e = blockIdx.x * 256 + threadIdx.x;   // grid covers E exactly
    int src = ei[e];
    int tgt = ei[NEDGES + e];

    const float4* eav = (const float4*)(eattr + (long long)e * 8);
    float4 ea0 = eav[0], ea1 = eav[1];
    float ea[8] = {ea0.x, ea0.y, ea0.z, ea0.w, ea1.x, ea1.y, ea1.z, ea1.w};

    // ---- layer 1 init: bias + folded edge contribution ----
    float acc[64];
    #pragma unroll
    for (int o = 0; o < 64; ++o) {
        float s = b1p[o];
        #pragma unroll
        for (int j = 0; j < 8; ++j)
            s += w1cp[o * 8 + j] * ea[j];
        acc[o] = s;
    }

    const float4* xsv = (const float4*)(xsrc + (long long)src * 64);
    const float4* xtv = (const float4*)(xtgt + (long long)tgt * 64);

    // ---- layer 1: x_source[src] contribution (k = 0..63) ----
    #pragma unroll
    for (int c = 0; c < 4; ++c) {
        float4 q0 = xsv[c * 4 + 0], q1 = xsv[c * 4 + 1];
        float4 q2 = xsv[c * 4 + 2], q3 = xsv[c * 4 + 3];
        float xv[16] = {q0.x, q0.y, q0.z, q0.w, q1.x, q1.y, q1.z, q1.w,
                        q2.x, q2.y, q2.z, q2.w, q3.x, q3.y, q3.z, q3.w};
        #pragma unroll
        for (int o = 0; o < 64; ++o) {
            #pragma unroll
            for (int kk = 0; kk < 16; ++kk)
                acc[o] += xv[kk] * W1[o * 192 + c * 16 + kk];
        }
    }

    // ---- layer 1: x_target[tgt] contribution (k = 64..127) ----
    #pragma unroll
    for (int c = 0; c < 4; ++c) {
        float4 q0 = xtv[c * 4 + 0], q1 = xtv[c * 4 + 1];
        float4 q2 = xtv[c * 4 + 2], q3 = xtv[c * 4 + 3];
        float xv[16] = {q0.x, q0.y, q0.z, q0.w, q1.x, q1.y, q1.z, q1.w,
                        q2.x, q2.y, q2.z, q2.w, q3.x, q3.y, q3.z, q3.w};
        #pragma unroll
        for (int o = 0; o < 64; ++o) {
            #pragma unroll
            for (int kk = 0; kk < 16; ++kk)
                acc[o] += xv[kk] * W1[o * 192 + 64 + c * 16 + kk];
        }
    }

    // ---- leaky relu ----
    #pragma unroll
    for (int o = 0; o < 64; ++o)
        acc[o] = fmaxf(acc[o], 0.f) + NEG_SLOPE * fminf(acc[o], 0.f);

    // ---- layer 2: 64 -> 32 ----
    float acc2[32];
    #pragma unroll
    for (int o2 = 0; o2 < 32; ++o2) {
        float s = b2[o2];
        #pragma unroll
        for (int k = 0; k < 64; ++k)
            s += acc[k] * W2[o2 * 64 + k];
        acc2[o2] = fmaxf(s, 0.f) + NEG_SLOPE * fminf(s, 0.f);
    }

    // ---- layer 3: 32 -> 1, relu ----
    float att = b3[0];
    #pragma unroll
    for (int k = 0; k < 32; ++k)
        att += acc2[k] * W3[k];
    att = fmaxf(att, 0.f);

    // ---- scatter: out[tgt] += att * x_source[src] ----
    if (att > 0.f) {
        float* op = out + (long long)tgt * 64;
        #pragma unroll
        for (int c = 0; c < 16; ++c) {
            float4 q = xsv[c];
            unsafeAtomicAdd(op + c * 4 + 0, att * q.x);
            unsafeAtomicAdd(op + c * 4 + 1, att * q.y);
            unsafeAtomicAdd(op + c * 4 + 2, att * q.z);
            unsafeAtomicAdd(op + c * 4 + 3, att * q.w);
        }
    }
}

// ---------------------------------------------------------------------------
extern "C" void kernel_launch(void* const* d_in, const int* in_sizes, int n_in,
                              void* d_out, int out_size, void* d_ws, size_t ws_size,
                              hipStream_t stream) {
    const float* x      = (const float*)d_in[0];
    const int*   ei     = (const int*)d_in[1];     // int64 in ref -> int32 here
    const float* eattr  = (const float*)d_in[2];
    const float* W_src  = (const float*)d_in[3];
    const float* b_src  = (const float*)d_in[4];
    const float* W_tgt  = (const float*)d_in[5];
    const float* b_tgt  = (const float*)d_in[6];
    const float* W_edge = (const float*)d_in[7];
    const float* b_edge = (const float*)d_in[8];
    const float* W1     = (const float*)d_in[9];
    const float* b1     = (const float*)d_in[10];
    const float* W2     = (const float*)d_in[11];
    const float* b2     = (const float*)d_in[12];
    const float* W3     = (const float*)d_in[13];
    const float* b3     = (const float*)d_in[14];
    float* out = (float*)d_out;

    float* xsrc = (float*)d_ws;                  // N*64
    float* xtgt = xsrc + (size_t)NNODES * 64;    // N*64
    float* w1cp = xtgt + (size_t)NNODES * 64;    // 512
    float* b1p  = w1cp + 512;                    // 64

    egat_precompute<<<1, 256, 0, stream>>>(W1, b1, W_edge, b_edge, w1cp, b1p);
    egat_node<<<2048, 256, 0, stream>>>(x, W_src, b_src, W_tgt, b_tgt,
                                        xsrc, xtgt, out);
    egat_edge<<<NEDGES / 256, 256, 0, stream>>>(ei, eattr, xsrc, xtgt,
                                                W1, w1cp, b1p, W2, b2, W3, b3, out);
}

// Round 3
// 1461.402 us; speedup vs baseline: 2.0265x; 2.0265x over previous
//
#include <hip/hip_runtime.h>

#define NNODES 100000
#define NEDGES 1600000
#define NEG_SLOPE 0.01f

// ---------------------------------------------------------------------------
// Kernel P: fold W_edge/b_edge into W1's last 64 columns.
// ---------------------------------------------------------------------------
__global__ void egat_precompute(const float* __restrict__ W1,
                                const float* __restrict__ b1,
                                const float* __restrict__ We,
                                const float* __restrict__ be,
                                float* __restrict__ w1cp,
                                float* __restrict__ b1p) {
    int tid = threadIdx.x;
    for (int idx = tid; idx < 512; idx += 256) {
        int o = idx >> 3, j = idx & 7;
        float s = 0.f;
        for (int t = 0; t < 64; ++t)
            s += W1[o * 192 + 128 + t] * We[t * 8 + j];
        w1cp[idx] = s;
    }
    if (tid < 64) {
        float s = b1[tid];
        for (int t = 0; t < 64; ++t)
            s += W1[tid * 192 + 128 + t] * be[t];
        b1p[tid] = s;
    }
}

// ---------------------------------------------------------------------------
// Zero the degree histogram.
// ---------------------------------------------------------------------------
__global__ void egat_zero(int* __restrict__ deg) {
    int i = blockIdx.x * 256 + threadIdx.x;
    if (i < NNODES) deg[i] = 0;
}

// ---------------------------------------------------------------------------
// Kernel N: x_source / x_target projections into workspace.
// ---------------------------------------------------------------------------
__global__ __launch_bounds__(256) void egat_node(
        const float* __restrict__ x,
        const float* __restrict__ Ws, const float* __restrict__ bs,
        const float* __restrict__ Wt, const float* __restrict__ bt,
        float* __restrict__ xsrc, float* __restrict__ xtgt) {
    __shared__ float2 Wb[64 * 64];      // 32 KiB
    __shared__ float  xrow[4][64];
    int tid = threadIdx.x;
    for (int idx = tid; idx < 4096; idx += 256) {
        int o = idx >> 6, k = idx & 63;
        Wb[k * 64 + o] = make_float2(Ws[idx], Wt[idx]);
    }
    __syncthreads();

    int w = tid >> 6, lane = tid & 63;
    float bsv = bs[lane], btv = bt[lane];

    for (int base = blockIdx.x * 4; base < NNODES; base += gridDim.x * 4) {
        int node = base + w;
        float xv = (node < NNODES) ? x[node * 64 + lane] : 0.f;
        xrow[w][lane] = xv;
        __syncthreads();

        float accs = bsv, acct = btv;
        #pragma unroll 8
        for (int k = 0; k < 64; ++k) {
            float xk = xrow[w][k];
            float2 wv = Wb[k * 64 + lane];
            accs += xk * wv.x;
            acct += xk * wv.y;
        }
        if (node < NNODES) {
            xsrc[node * 64 + lane] = accs;
            xtgt[node * 64 + lane] = acct;
        }
        __syncthreads();
    }
}

// ---------------------------------------------------------------------------
// Kernel E: per-edge attention MLP -> att[e]; gated degree histogram.
// No f32 atomics here anymore.
// ---------------------------------------------------------------------------
__global__ __launch_bounds__(256) void egat_edge(
        const int* __restrict__ ei,           // [2, E] (int32)
        const float* __restrict__ eattr,      // [E, 8]
        const float* __restrict__ xsrc,       // [N, 64]
        const float* __restrict__ xtgt,       // [N, 64]
        const float* __restrict__ W1,         // [64, 192]
        const float* __restrict__ w1cp,       // [64, 8]
        const float* __restrict__ b1p,        // [64]
        const float* __restrict__ W2,         // [32, 64]
        const float* __restrict__ b2,         // [32]
        const float* __restrict__ W3,         // [1, 32]
        const float* __restrict__ b3,         // [1]
        float* __restrict__ attv,             // [E]
        int* __restrict__ deg) {              // [N]
    int e = blockIdx.x * 256 + threadIdx.x;
    int src = ei[e];
    int tgt = ei[NEDGES + e];

    const float4* eav = (const float4*)(eattr + (long long)e * 8);
    float4 ea0 = eav[0], ea1 = eav[1];
    float ea[8] = {ea0.x, ea0.y, ea0.z, ea0.w, ea1.x, ea1.y, ea1.z, ea1.w};

    float acc[64];
    #pragma unroll
    for (int o = 0; o < 64; ++o) {
        float s = b1p[o];
        #pragma unroll
        for (int j = 0; j < 8; ++j)
            s += w1cp[o * 8 + j] * ea[j];
        acc[o] = s;
    }

    const float4* xsv = (const float4*)(xsrc + (long long)src * 64);
    const float4* xtv = (const float4*)(xtgt + (long long)tgt * 64);

    #pragma unroll
    for (int c = 0; c < 4; ++c) {
        float4 q0 = xsv[c * 4 + 0], q1 = xsv[c * 4 + 1];
        float4 q2 = xsv[c * 4 + 2], q3 = xsv[c * 4 + 3];
        float xv[16] = {q0.x, q0.y, q0.z, q0.w, q1.x, q1.y, q1.z, q1.w,
                        q2.x, q2.y, q2.z, q2.w, q3.x, q3.y, q3.z, q3.w};
        #pragma unroll
        for (int o = 0; o < 64; ++o) {
            #pragma unroll
            for (int kk = 0; kk < 16; ++kk)
                acc[o] += xv[kk] * W1[o * 192 + c * 16 + kk];
        }
    }
    #pragma unroll
    for (int c = 0; c < 4; ++c) {
        float4 q0 = xtv[c * 4 + 0], q1 = xtv[c * 4 + 1];
        float4 q2 = xtv[c * 4 + 2], q3 = xtv[c * 4 + 3];
        float xv[16] = {q0.x, q0.y, q0.z, q0.w, q1.x, q1.y, q1.z, q1.w,
                        q2.x, q2.y, q2.z, q2.w, q3.x, q3.y, q3.z, q3.w};
        #pragma unroll
        for (int o = 0; o < 64; ++o) {
            #pragma unroll
            for (int kk = 0; kk < 16; ++kk)
                acc[o] += xv[kk] * W1[o * 192 + 64 + c * 16 + kk];
        }
    }

    #pragma unroll
    for (int o = 0; o < 64; ++o)
        acc[o] = fmaxf(acc[o], 0.f) + NEG_SLOPE * fminf(acc[o], 0.f);

    float acc2[32];
    #pragma unroll
    for (int o2 = 0; o2 < 32; ++o2) {
        float s = b2[o2];
        #pragma unroll
        for (int k = 0; k < 64; ++k)
            s += acc[k] * W2[o2 * 64 + k];
        acc2[o2] = fmaxf(s, 0.f) + NEG_SLOPE * fminf(s, 0.f);
    }

    float att = b3[0];
    #pragma unroll
    for (int k = 0; k < 32; ++k)
        att += acc2[k] * W3[k];
    att = fmaxf(att, 0.f);

    attv[e] = att;
    if (att > 0.f) atomicAdd(&deg[tgt], 1);   // int atomic, L2-resident
}

// ---------------------------------------------------------------------------
// Exclusive scan of deg -> offs, and cursor = offs. Single block, 1024 thr.
// ---------------------------------------------------------------------------
__global__ __launch_bounds__(1024) void egat_scan(
        const int* __restrict__ deg, int* __restrict__ offs,
        int* __restrict__ cursor) {
    __shared__ int wsum[16];
    __shared__ int sbase;
    int tid = threadIdx.x, lane = tid & 63, w = tid >> 6;
    if (tid == 0) sbase = 0;
    __syncthreads();
    for (int base = 0; base < NNODES; base += 1024) {
        int i = base + tid;
        int v = (i < NNODES) ? deg[i] : 0;
        int incl = v;
        #pragma unroll
        for (int s = 1; s < 64; s <<= 1) {
            int t = __shfl_up(incl, s, 64);
            if (lane >= s) incl += t;
        }
        if (lane == 63) wsum[w] = incl;
        __syncthreads();
        if (w == 0 && lane < 16) {
            int xx = wsum[lane];
            int sc = xx;
            #pragma unroll
            for (int s = 1; s < 16; s <<= 1) {
                int t = __shfl_up(sc, s, 16);
                if ((lane & 15) >= s) sc += t;
            }
            wsum[lane] = sc - xx;   // exclusive wave offset
        }
        __syncthreads();
        int woff = wsum[w];
        int excl = sbase + woff + incl - v;
        if (i < NNODES) { offs[i] = excl; cursor[i] = excl; }
        __syncthreads();
        if (tid == 1023) sbase += woff + incl;  // chunk total
        __syncthreads();
    }
}

// ---------------------------------------------------------------------------
// Scatter gated edges into CSR slots as {att, src}.
// ---------------------------------------------------------------------------
__global__ __launch_bounds__(256) void egat_scatter(
        const int* __restrict__ ei, const float* __restrict__ attv,
        int* __restrict__ cursor, float2* __restrict__ csr) {
    int e = blockIdx.x * 256 + threadIdx.x;
    float att = attv[e];
    if (att <= 0.f) return;
    int src = ei[e];
    int tgt = ei[NEDGES + e];
    int pos = atomicAdd(&cursor[tgt], 1);
    csr[pos] = make_float2(att, __int_as_float(src));
}

// ---------------------------------------------------------------------------
// Gather: one wave per node; lanes = channels. No atomics.
// out[n] = xtgt[n] + sum_{gated incoming e} att[e] * xsrc[src[e]]
// ---------------------------------------------------------------------------
__global__ __launch_bounds__(256) void egat_gather(
        const float2* __restrict__ csr, const int* __restrict__ offs,
        const int* __restrict__ cursor, const float* __restrict__ xsrc,
        const float* __restrict__ xtgt, float* __restrict__ out) {
    int wid = (blockIdx.x * 256 + threadIdx.x) >> 6;
    int lane = threadIdx.x & 63;
    int beg = offs[wid];
    int end = cursor[wid];        // cursor has advanced to segment end
    float acc = xtgt[wid * 64 + lane];
    int i = beg;
    for (; i + 1 < end; i += 2) {
        float2 a = csr[i], b = csr[i + 1];
        int sa = __float_as_int(a.y), sb = __float_as_int(b.y);
        acc += a.x * xsrc[sa * 64 + lane];
        acc += b.x * xsrc[sb * 64 + lane];
    }
    if (i < end) {
        float2 a = csr[i];
        acc += a.x * xsrc[__float_as_int(a.y) * 64 + lane];
    }
    out[wid * 64 + lane] = acc;
}

// ---------------------------------------------------------------------------
extern "C" void kernel_launch(void* const* d_in, const int* in_sizes, int n_in,
                              void* d_out, int out_size, void* d_ws, size_t ws_size,
                              hipStream_t stream) {
    const float* x      = (const float*)d_in[0];
    const int*   ei     = (const int*)d_in[1];     // int64 in ref -> int32 here
    const float* eattr  = (const float*)d_in[2];
    const float* W_src  = (const float*)d_in[3];
    const float* b_src  = (const float*)d_in[4];
    const float* W_tgt  = (const float*)d_in[5];
    const float* b_tgt  = (const float*)d_in[6];
    const float* W_edge = (const float*)d_in[7];
    const float* b_edge = (const float*)d_in[8];
    const float* W1     = (const float*)d_in[9];
    const float* b1     = (const float*)d_in[10];
    const float* W2     = (const float*)d_in[11];
    const float* b2     = (const float*)d_in[12];
    const float* W3     = (const float*)d_in[13];
    const float* b3     = (const float*)d_in[14];
    float* out = (float*)d_out;

    // workspace layout (floats)
    float* xsrc = (float*)d_ws;                        // N*64     = 6.4M
    float* xtgt = xsrc + (size_t)NNODES * 64;          // N*64     = 6.4M
    float* attv = xtgt + (size_t)NNODES * 64;          // E        = 1.6M
    float2* csr = (float2*)(attv + (size_t)NEDGES);    // E float2 = 3.2M floats (8B aligned: 14.4M floats offset)
    int*   deg    = (int*)(csr + (size_t)NEDGES);      // N
    int*   offs   = deg + NNODES;                      // N
    int*   cursor = offs + NNODES;                     // N
    float* w1cp   = (float*)(cursor + NNODES);         // 512
    float* b1p    = w1cp + 512;                        // 64

    egat_precompute<<<1, 256, 0, stream>>>(W1, b1, W_edge, b_edge, w1cp, b1p);
    egat_zero<<<(NNODES + 255) / 256, 256, 0, stream>>>(deg);
    egat_node<<<2048, 256, 0, stream>>>(x, W_src, b_src, W_tgt, b_tgt, xsrc, xtgt);
    egat_edge<<<NEDGES / 256, 256, 0, stream>>>(ei, eattr, xsrc, xtgt,
                                                W1, w1cp, b1p, W2, b2, W3, b3,
                                                attv, deg);
    egat_scan<<<1, 1024, 0, stream>>>(deg, offs, cursor);
    egat_scatter<<<NEDGES / 256, 256, 0, stream>>>(ei, attv, cursor, csr);
    egat_gather<<<(NNODES * 64) / 256, 256, 0, stream>>>(csr, offs, cursor,
                                                         xsrc, xtgt, out);
}

// Round 4
// 549.801 us; speedup vs baseline: 5.3866x; 2.6581x over previous
//
#include <hip/hip_runtime.h>

#define NNODES 100000
#define NEDGES 1600000
#define NEG_SLOPE 0.01f

// round-to-nearest-even f32 -> bf16 (as ushort)
static __device__ inline unsigned short f2bf(float f) {
    unsigned u = __float_as_uint(f);
    u += 0x7fffu + ((u >> 16) & 1u);
    return (unsigned short)(u >> 16);
}
static __device__ inline float bf_lo(unsigned u) { return __uint_as_float(u << 16); }
static __device__ inline float bf_hi(unsigned u) { return __uint_as_float(u & 0xffff0000u); }

// ---------------------------------------------------------------------------
// Kernel P: algebraic folding.
//   Ms = W1[:,0:64]   @ W_src   (64x64)   -> ps path (from raw x)
//   Mt = W1[:,64:128] @ W_tgt   (64x64)   -> pt path
//   w1cp = W1[:,128:192] @ W_edge (64x8)
//   btot = b1 + W1[:,0:64]@b_src + W1[:,64:128]@b_tgt + W1[:,128:192]@b_edge
// ---------------------------------------------------------------------------
__global__ void egat_precompute(const float* __restrict__ W1,
                                const float* __restrict__ b1,
                                const float* __restrict__ Ws,
                                const float* __restrict__ bs,
                                const float* __restrict__ Wt,
                                const float* __restrict__ bt,
                                const float* __restrict__ We,
                                const float* __restrict__ be,
                                float* __restrict__ Ms, float* __restrict__ Mt,
                                float* __restrict__ w1cp, float* __restrict__ btot) {
    int tid = threadIdx.x;
    for (int idx = tid; idx < 4096; idx += 256) {
        int o = idx >> 6, i = idx & 63;
        float s = 0.f, t = 0.f;
        for (int k = 0; k < 64; ++k) {
            s += W1[o * 192 + k]      * Ws[k * 64 + i];
            t += W1[o * 192 + 64 + k] * Wt[k * 64 + i];
        }
        Ms[idx] = s;
        Mt[idx] = t;
    }
    for (int idx = tid; idx < 512; idx += 256) {
        int o = idx >> 3, j = idx & 7;
        float s = 0.f;
        for (int t = 0; t < 64; ++t)
            s += W1[o * 192 + 128 + t] * We[t * 8 + j];
        w1cp[idx] = s;
    }
    if (tid < 64) {
        float s = b1[tid];
        for (int k = 0; k < 64; ++k) {
            s += W1[tid * 192 + k]       * bs[k];
            s += W1[tid * 192 + 64 + k]  * bt[k];
        }
        for (int t = 0; t < 64; ++t)
            s += W1[tid * 192 + 128 + t] * be[t];
        btot[tid] = s;
    }
}

__global__ void egat_zero(int* __restrict__ deg) {
    int i = blockIdx.x * 256 + threadIdx.x;
    if (i < NNODES) deg[i] = 0;
}

// ---------------------------------------------------------------------------
// Kernel N1: xsrc = x@Ws^T + bs, xtgt = x@Wt^T + bt  (fp32, for messages/output)
// ---------------------------------------------------------------------------
__global__ __launch_bounds__(256) void egat_node(
        const float* __restrict__ x,
        const float* __restrict__ Ws, const float* __restrict__ bs,
        const float* __restrict__ Wt, const float* __restrict__ bt,
        float* __restrict__ xsrc, float* __restrict__ xtgt) {
    __shared__ float2 Wb[64 * 64];      // 32 KiB, Wb[k][o] = {Ws[o][k], Wt[o][k]}
    __shared__ float  xrow[4][64];
    int tid = threadIdx.x;
    for (int idx = tid; idx < 4096; idx += 256) {
        int o = idx >> 6, k = idx & 63;
        Wb[k * 64 + o] = make_float2(Ws[idx], Wt[idx]);
    }
    __syncthreads();

    int w = tid >> 6, lane = tid & 63;
    float bsv = bs[lane], btv = bt[lane];

    for (int base = blockIdx.x * 4; base < NNODES; base += gridDim.x * 4) {
        int node = base + w;
        float xv = (node < NNODES) ? x[node * 64 + lane] : 0.f;
        xrow[w][lane] = xv;
        __syncthreads();
        float accs = bsv, acct = btv;
        #pragma unroll 8
        for (int k = 0; k < 64; ++k) {
            float xk = xrow[w][k];
            float2 wv = Wb[k * 64 + lane];
            accs += xk * wv.x;
            acct += xk * wv.y;
        }
        if (node < NNODES) {
            xsrc[node * 64 + lane] = accs;
            xtgt[node * 64 + lane] = acct;
        }
        __syncthreads();
    }
}

// ---------------------------------------------------------------------------
// Kernel N2: ps = x@Ms^T + btot, pt = x@Mt^T  (bf16, attention-path only)
// ---------------------------------------------------------------------------
__global__ __launch_bounds__(256) void egat_nodeP(
        const float* __restrict__ x,
        const float* __restrict__ Ms, const float* __restrict__ Mt,
        const float* __restrict__ btot,
        unsigned short* __restrict__ ps, unsigned short* __restrict__ pt) {
    __shared__ float2 Wb[64 * 64];      // Wb[k][o] = {Ms[o][k], Mt[o][k]}
    __shared__ float  xrow[4][64];
    int tid = threadIdx.x;
    for (int idx = tid; idx < 4096; idx += 256) {
        int o = idx >> 6, k = idx & 63;
        Wb[k * 64 + o] = make_float2(Ms[idx], Mt[idx]);
    }
    __syncthreads();

    int w = tid >> 6, lane = tid & 63;
    float bv = btot[lane];

    for (int base = blockIdx.x * 4; base < NNODES; base += gridDim.x * 4) {
        int node = base + w;
        float xv = (node < NNODES) ? x[node * 64 + lane] : 0.f;
        xrow[w][lane] = xv;
        __syncthreads();
        float accp = bv, accq = 0.f;
        #pragma unroll 8
        for (int k = 0; k < 64; ++k) {
            float xk = xrow[w][k];
            float2 wv = Wb[k * 64 + lane];
            accp += xk * wv.x;
            accq += xk * wv.y;
        }
        if (node < NNODES) {
            ps[node * 64 + lane] = f2bf(accp);
            pt[node * 64 + lane] = f2bf(accq);
        }
        __syncthreads();
    }
}

// ---------------------------------------------------------------------------
// Kernel E: light per-edge MLP.
//   h1 = leakyrelu(ps[src] + pt[tgt] + w1cp@ea); h2 = leakyrelu(W2@h1 + b2);
//   att = relu(W3@h2 + b3) -> attv[e]; gated degree histogram.
// ---------------------------------------------------------------------------
__global__ __launch_bounds__(256) void egat_edge(
        const int* __restrict__ ei,                 // [2, E] int32
        const float* __restrict__ eattr,            // [E, 8]
        const unsigned short* __restrict__ ps,      // [N, 64] bf16
        const unsigned short* __restrict__ pt,      // [N, 64] bf16
        const float* __restrict__ w1cp,             // [64, 8]
        const float* __restrict__ W2,               // [32, 64]
        const float* __restrict__ b2,               // [32]
        const float* __restrict__ W3,               // [1, 32]
        const float* __restrict__ b3,               // [1]
        float* __restrict__ attv,                   // [E]
        int* __restrict__ deg) {                    // [N]
    int e = blockIdx.x * 256 + threadIdx.x;
    int src = ei[e];
    int tgt = ei[NEDGES + e];

    const float4* eav = (const float4*)(eattr + (long long)e * 8);
    float4 ea0 = eav[0], ea1 = eav[1];
    float ea[8] = {ea0.x, ea0.y, ea0.z, ea0.w, ea1.x, ea1.y, ea1.z, ea1.w};

    const uint4* pr = (const uint4*)(ps + (size_t)src * 64);   // 8 x 16B
    const uint4* qr = (const uint4*)(pt + (size_t)tgt * 64);

    // edge-attr contribution (wave-uniform weight s_loads)
    float acc[64];
    #pragma unroll
    for (int o = 0; o < 64; ++o) {
        float s = 0.f;
        #pragma unroll
        for (int j = 0; j < 8; ++j)
            s += w1cp[o * 8 + j] * ea[j];
        acc[o] = s;
    }

    // + ps[src] + pt[tgt]  (bf16 unpack: elem 2c from low half, 2c+1 from high)
    #pragma unroll
    for (int r = 0; r < 8; ++r) {
        uint4 p = pr[r], q = qr[r];
        unsigned pu[4] = {p.x, p.y, p.z, p.w};
        unsigned qu[4] = {q.x, q.y, q.z, q.w};
        #pragma unroll
        for (int c = 0; c < 4; ++c) {
            acc[r * 8 + 2 * c]     += bf_lo(pu[c]) + bf_lo(qu[c]);
            acc[r * 8 + 2 * c + 1] += bf_hi(pu[c]) + bf_hi(qu[c]);
        }
    }

    #pragma unroll
    for (int o = 0; o < 64; ++o)
        acc[o] = fmaxf(acc[o], 0.f) + NEG_SLOPE * fminf(acc[o], 0.f);

    float acc2[32];
    #pragma unroll
    for (int o2 = 0; o2 < 32; ++o2) {
        float s = b2[o2];
        #pragma unroll
        for (int k = 0; k < 64; ++k)
            s += acc[k] * W2[o2 * 64 + k];
        acc2[o2] = fmaxf(s, 0.f) + NEG_SLOPE * fminf(s, 0.f);
    }

    float att = b3[0];
    #pragma unroll
    for (int k = 0; k < 32; ++k)
        att += acc2[k] * W3[k];
    att = fmaxf(att, 0.f);

    attv[e] = att;
    if (att > 0.f) atomicAdd(&deg[tgt], 1);
}

// ---------------------------------------------------------------------------
// Exclusive scan of deg -> offs, cursor. Single block, 1024 threads.
// ---------------------------------------------------------------------------
__global__ __launch_bounds__(1024) void egat_scan(
        const int* __restrict__ deg, int* __restrict__ offs,
        int* __restrict__ cursor) {
    __shared__ int wsum[16];
    __shared__ int sbase;
    int tid = threadIdx.x, lane = tid & 63, w = tid >> 6;
    if (tid == 0) sbase = 0;
    __syncthreads();
    for (int base = 0; base < NNODES; base += 1024) {
        int i = base + tid;
        int v = (i < NNODES) ? deg[i] : 0;
        int incl = v;
        #pragma unroll
        for (int s = 1; s < 64; s <<= 1) {
            int t = __shfl_up(incl, s, 64);
            if (lane >= s) incl += t;
        }
        if (lane == 63) wsum[w] = incl;
        __syncthreads();
        if (w == 0 && lane < 16) {
            int xx = wsum[lane];
            int sc = xx;
            #pragma unroll
            for (int s = 1; s < 16; s <<= 1) {
                int t = __shfl_up(sc, s, 16);
                if ((lane & 15) >= s) sc += t;
            }
            wsum[lane] = sc - xx;
        }
        __syncthreads();
        int woff = wsum[w];
        int excl = sbase + woff + incl - v;
        if (i < NNODES) { offs[i] = excl; cursor[i] = excl; }
        __syncthreads();
        if (tid == 1023) sbase += woff + incl;
        __syncthreads();
    }
}

// ---------------------------------------------------------------------------
// Scatter gated edges into CSR slots as {att, src}.
// ---------------------------------------------------------------------------
__global__ __launch_bounds__(256) void egat_scatter(
        const int* __restrict__ ei, const float* __restrict__ attv,
        int* __restrict__ cursor, float2* __restrict__ csr) {
    int e = blockIdx.x * 256 + threadIdx.x;
    float att = attv[e];
    if (att <= 0.f) return;
    int src = ei[e];
    int tgt = ei[NEDGES + e];
    int pos = atomicAdd(&cursor[tgt], 1);
    csr[pos] = make_float2(att, __int_as_float(src));
}

// ---------------------------------------------------------------------------
// Gather: one wave per node; lanes = channels; coalesced row reads, no atomics.
// ---------------------------------------------------------------------------
__global__ __launch_bounds__(256) void egat_gather(
        const float2* __restrict__ csr, const int* __restrict__ offs,
        const int* __restrict__ cursor, const float* __restrict__ xsrc,
        const float* __restrict__ xtgt, float* __restrict__ out) {
    int wid = (blockIdx.x * 256 + threadIdx.x) >> 6;
    int lane = threadIdx.x & 63;
    int beg = offs[wid];
    int end = cursor[wid];
    float acc = xtgt[wid * 64 + lane];
    int i = beg;
    for (; i + 3 < end; i += 4) {
        float2 a = csr[i], b = csr[i + 1], c = csr[i + 2], d = csr[i + 3];
        acc += a.x * xsrc[__float_as_int(a.y) * 64 + lane];
        acc += b.x * xsrc[__float_as_int(b.y) * 64 + lane];
        acc += c.x * xsrc[__float_as_int(c.y) * 64 + lane];
        acc += d.x * xsrc[__float_as_int(d.y) * 64 + lane];
    }
    for (; i < end; ++i) {
        float2 a = csr[i];
        acc += a.x * xsrc[__float_as_int(a.y) * 64 + lane];
    }
    out[wid * 64 + lane] = acc;
}

// ---------------------------------------------------------------------------
extern "C" void kernel_launch(void* const* d_in, const int* in_sizes, int n_in,
                              void* d_out, int out_size, void* d_ws, size_t ws_size,
                              hipStream_t stream) {
    const float* x      = (const float*)d_in[0];
    const int*   ei     = (const int*)d_in[1];     // int64 in ref -> int32 here
    const float* eattr  = (const float*)d_in[2];
    const float* W_src  = (const float*)d_in[3];
    const float* b_src  = (const float*)d_in[4];
    const float* W_tgt  = (const float*)d_in[5];
    const float* b_tgt  = (const float*)d_in[6];
    const float* W_edge = (const float*)d_in[7];
    const float* b_edge = (const float*)d_in[8];
    const float* W1     = (const float*)d_in[9];
    const float* b1     = (const float*)d_in[10];
    const float* W2     = (const float*)d_in[11];
    const float* b2     = (const float*)d_in[12];
    const float* W3     = (const float*)d_in[13];
    const float* b3     = (const float*)d_in[14];
    float* out = (float*)d_out;

    // workspace layout
    float* xsrc          = (float*)d_ws;                         // N*64 f32
    float* xtgt          = xsrc + (size_t)NNODES * 64;           // N*64 f32
    unsigned short* ps   = (unsigned short*)(xtgt + (size_t)NNODES * 64); // N*64 bf16
    unsigned short* pt   = ps + (size_t)NNODES * 64;             // N*64 bf16
    float* attv          = (float*)(pt + (size_t)NNODES * 64);   // E f32
    float2* csr          = (float2*)(attv + (size_t)NEDGES);     // E float2
    int* deg             = (int*)(csr + (size_t)NEDGES);         // N
    int* offs            = deg + NNODES;                         // N
    int* cursor          = offs + NNODES;                        // N
    float* Ms            = (float*)(cursor + NNODES);            // 4096
    float* Mt            = Ms + 4096;                            // 4096
    float* w1cp          = Mt + 4096;                            // 512
    float* btot          = w1cp + 512;                           // 64

    egat_precompute<<<1, 256, 0, stream>>>(W1, b1, W_src, b_src, W_tgt, b_tgt,
                                           W_edge, b_edge, Ms, Mt, w1cp, btot);
    egat_zero<<<(NNODES + 255) / 256, 256, 0, stream>>>(deg);
    egat_node<<<2048, 256, 0, stream>>>(x, W_src, b_src, W_tgt, b_tgt, xsrc, xtgt);
    egat_nodeP<<<2048, 256, 0, stream>>>(x, Ms, Mt, btot, ps, pt);
    egat_edge<<<NEDGES / 256, 256, 0, stream>>>(ei, eattr, ps, pt,
                                                w1cp, W2, b2, W3, b3, attv, deg);
    egat_scan<<<1, 1024, 0, stream>>>(deg, offs, cursor);
    egat_scatter<<<NEDGES / 256, 256, 0, stream>>>(ei, attv, cursor, csr);
    egat_gather<<<(NNODES * 64) / 256, 256, 0, stream>>>(csr, offs, cursor,
                                                         xsrc, xtgt, out);
}

// Round 5
// 441.098 us; speedup vs baseline: 6.7141x; 1.2464x over previous
//
#include <hip/hip_runtime.h>
#include <hip/hip_bf16.h>

#define NNODES 100000
#define NEDGES 1600000
#define NEG_SLOPE 0.01f

typedef __attribute__((ext_vector_type(8))) short short8;
typedef __attribute__((ext_vector_type(4))) float floatx4;

// round-to-nearest-even f32 -> bf16 (as ushort)
static __device__ inline unsigned short f2bf(float f) {
    unsigned u = __float_as_uint(f);
    u += 0x7fffu + ((u >> 16) & 1u);
    return (unsigned short)(u >> 16);
}
static __device__ inline float bf_lo(unsigned u) { return __uint_as_float(u << 16); }
static __device__ inline float bf_hi(unsigned u) { return __uint_as_float(u & 0xffff0000u); }

// packed f32x2 -> bf16x2 (single HW instruction; D.lo=cvt(S0), D.hi=cvt(S1))
static __device__ inline unsigned cvtpk_bf16(float a, float b) {
    unsigned r;
    asm("v_cvt_pk_bf16_f32 %0, %1, %2" : "=v"(r) : "v"(a), "v"(b));
    return r;
}

// ---------------------------------------------------------------------------
// Kernel P: algebraic folding.
//   Ms = W1[:,0:64]@W_src, Mt = W1[:,64:128]@W_tgt (64x64)
//   w1cp = W1[:,128:192]@W_edge (64x8)
//   btot = b1 + W1[:,0:64]@b_src + W1[:,64:128]@b_tgt + W1[:,128:192]@b_edge
// ---------------------------------------------------------------------------
__global__ void egat_precompute(const float* __restrict__ W1,
                                const float* __restrict__ b1,
                                const float* __restrict__ Ws,
                                const float* __restrict__ bs,
                                const float* __restrict__ Wt,
                                const float* __restrict__ bt,
                                const float* __restrict__ We,
                                const float* __restrict__ be,
                                float* __restrict__ Ms, float* __restrict__ Mt,
                                float* __restrict__ w1cp, float* __restrict__ btot) {
    int tid = threadIdx.x;
    for (int idx = tid; idx < 4096; idx += 256) {
        int o = idx >> 6, i = idx & 63;
        float s = 0.f, t = 0.f;
        for (int k = 0; k < 64; ++k) {
            s += W1[o * 192 + k]      * Ws[k * 64 + i];
            t += W1[o * 192 + 64 + k] * Wt[k * 64 + i];
        }
        Ms[idx] = s;
        Mt[idx] = t;
    }
    for (int idx = tid; idx < 512; idx += 256) {
        int o = idx >> 3, j = idx & 7;
        float s = 0.f;
        for (int t = 0; t < 64; ++t)
            s += W1[o * 192 + 128 + t] * We[t * 8 + j];
        w1cp[idx] = s;
    }
    if (tid < 64) {
        float s = b1[tid];
        for (int k = 0; k < 64; ++k) {
            s += W1[tid * 192 + k]       * bs[k];
            s += W1[tid * 192 + 64 + k]  * bt[k];
        }
        for (int t = 0; t < 64; ++t)
            s += W1[tid * 192 + 128 + t] * be[t];
        btot[tid] = s;
    }
}

__global__ void egat_zero(int* __restrict__ deg) {
    int i = blockIdx.x * 256 + threadIdx.x;
    if (i < NNODES) deg[i] = 0;
}

// ---------------------------------------------------------------------------
// Kernel N1: xsrc = x@Ws^T + bs, xtgt = x@Wt^T + bt  (fp32)
// ---------------------------------------------------------------------------
__global__ __launch_bounds__(256) void egat_node(
        const float* __restrict__ x,
        const float* __restrict__ Ws, const float* __restrict__ bs,
        const float* __restrict__ Wt, const float* __restrict__ bt,
        float* __restrict__ xsrc, float* __restrict__ xtgt) {
    __shared__ float2 Wb[64 * 64];
    __shared__ float  xrow[4][64];
    int tid = threadIdx.x;
    for (int idx = tid; idx < 4096; idx += 256) {
        int o = idx >> 6, k = idx & 63;
        Wb[k * 64 + o] = make_float2(Ws[idx], Wt[idx]);
    }
    __syncthreads();

    int w = tid >> 6, lane = tid & 63;
    float bsv = bs[lane], btv = bt[lane];

    for (int base = blockIdx.x * 4; base < NNODES; base += gridDim.x * 4) {
        int node = base + w;
        float xv = (node < NNODES) ? x[node * 64 + lane] : 0.f;
        xrow[w][lane] = xv;
        __syncthreads();
        float accs = bsv, acct = btv;
        #pragma unroll 8
        for (int k = 0; k < 64; ++k) {
            float xk = xrow[w][k];
            float2 wv = Wb[k * 64 + lane];
            accs += xk * wv.x;
            acct += xk * wv.y;
        }
        if (node < NNODES) {
            xsrc[node * 64 + lane] = accs;
            xtgt[node * 64 + lane] = acct;
        }
        __syncthreads();
    }
}

// ---------------------------------------------------------------------------
// Kernel N2: ps = x@Ms^T + btot, pt = x@Mt^T  (bf16)
// ---------------------------------------------------------------------------
__global__ __launch_bounds__(256) void egat_nodeP(
        const float* __restrict__ x,
        const float* __restrict__ Ms, const float* __restrict__ Mt,
        const float* __restrict__ btot,
        unsigned short* __restrict__ ps, unsigned short* __restrict__ pt) {
    __shared__ float2 Wb[64 * 64];
    __shared__ float  xrow[4][64];
    int tid = threadIdx.x;
    for (int idx = tid; idx < 4096; idx += 256) {
        int o = idx >> 6, k = idx & 63;
        Wb[k * 64 + o] = make_float2(Ms[idx], Mt[idx]);
    }
    __syncthreads();

    int w = tid >> 6, lane = tid & 63;
    float bv = btot[lane];

    for (int base = blockIdx.x * 4; base < NNODES; base += gridDim.x * 4) {
        int node = base + w;
        float xv = (node < NNODES) ? x[node * 64 + lane] : 0.f;
        xrow[w][lane] = xv;
        __syncthreads();
        float accp = bv, accq = 0.f;
        #pragma unroll 8
        for (int k = 0; k < 64; ++k) {
            float xk = xrow[w][k];
            float2 wv = Wb[k * 64 + lane];
            accp += xk * wv.x;
            accq += xk * wv.y;
        }
        if (node < NNODES) {
            ps[node * 64 + lane] = f2bf(accp);
            pt[node * 64 + lane] = f2bf(accq);
        }
        __syncthreads();
    }
}

// ---------------------------------------------------------------------------
// Kernel E: per-edge attention with MFMA layer-2.
// Phase 1 (per thread = 1 edge): h1 = lrelu(ps[src]+pt[tgt]+w1cp@ea) -> bf16
//   -> XOR-swizzled LDS row (B^T fragment layout for mfma).
// Phase 2 (per wave = 64 edges): H2 = W2·H1 via 16 x mfma_f32_16x16x32_bf16
//   (A = W2 [ch][k], B = H1^T [k][edge]); D: col=edge(lane&15), row=ch.
//   Per-lane W3 dot over its 8 channels, 2 shfl_xor to finish, relu, write.
// ---------------------------------------------------------------------------
__global__ __launch_bounds__(256) void egat_edge(
        const int* __restrict__ ei,                 // [2, E] int32
        const float* __restrict__ eattr,            // [E, 8]
        const unsigned short* __restrict__ ps,      // [N, 64] bf16
        const unsigned short* __restrict__ pt,      // [N, 64] bf16
        const float* __restrict__ w1cp,             // [64, 8]
        const float* __restrict__ W2,               // [32, 64]
        const float* __restrict__ b2,               // [32]
        const float* __restrict__ W3,               // [1, 32]
        const float* __restrict__ b3,               // [1]
        float* __restrict__ attv,                   // [E]
        int* __restrict__ deg) {                    // [N]
    __shared__ uint4 H[4 * 64 * 8];   // 32 KiB: per-wave [64 rows][8 chunks] bf16
    const int tid = threadIdx.x;
    const int w = tid >> 6, l = tid & 63;
    const int e = blockIdx.x * 256 + tid;
    const int E0 = blockIdx.x * 256 + w * 64;

    int src = ei[e];
    int tgt = ei[NEDGES + e];

    // ---- A-frags from W2 (loaded once, bf16) ----
    // afrag[r'][kk]: lane l -> W2[16r' + (l&15)][32kk + 8(l>>4) + j], j=0..7
    short8 afrag[2][2];
    #pragma unroll
    for (int rp = 0; rp < 2; ++rp) {
        #pragma unroll
        for (int kk = 0; kk < 2; ++kk) {
            const float* wp = W2 + (16 * rp + (l & 15)) * 64 + 32 * kk + 8 * (l >> 4);
            float4 f0 = *(const float4*)wp;
            float4 f1 = *(const float4*)(wp + 4);
            union { unsigned u[4]; short8 s; } cv;
            cv.u[0] = cvtpk_bf16(f0.x, f0.y);
            cv.u[1] = cvtpk_bf16(f0.z, f0.w);
            cv.u[2] = cvtpk_bf16(f1.x, f1.y);
            cv.u[3] = cvtpk_bf16(f1.z, f1.w);
            afrag[rp][kk] = cv.s;
        }
    }
    // epilogue per-lane constants: channels 4g+j and 16+4g+j (g = l>>4)
    const int g = l >> 4;
    float w30[4], w31[4], b20[4], b21[4];
    #pragma unroll
    for (int j = 0; j < 4; ++j) {
        w30[j] = W3[4 * g + j];       w31[j] = W3[16 + 4 * g + j];
        b20[j] = b2[4 * g + j];       b21[j] = b2[16 + 4 * g + j];
    }
    const float b3v = b3[0];

    // ---- phase 1: h1 for own edge ----
    const float4* eav = (const float4*)(eattr + (long long)e * 8);
    float4 ea0 = eav[0], ea1 = eav[1];
    float ea[8] = {ea0.x, ea0.y, ea0.z, ea0.w, ea1.x, ea1.y, ea1.z, ea1.w};

    float acc[64];
    #pragma unroll
    for (int o = 0; o < 64; ++o) {
        float s = 0.f;
        #pragma unroll
        for (int j = 0; j < 8; ++j)
            s += w1cp[o * 8 + j] * ea[j];
        acc[o] = s;
    }
    const uint4* pr = (const uint4*)(ps + (size_t)src * 64);
    const uint4* qr = (const uint4*)(pt + (size_t)tgt * 64);
    #pragma unroll
    for (int r = 0; r < 8; ++r) {
        uint4 p = pr[r], q = qr[r];
        unsigned pu[4] = {p.x, p.y, p.z, p.w};
        unsigned qu[4] = {q.x, q.y, q.z, q.w};
        #pragma unroll
        for (int c = 0; c < 4; ++c) {
            acc[r * 8 + 2 * c]     += bf_lo(pu[c]) + bf_lo(qu[c]);
            acc[r * 8 + 2 * c + 1] += bf_hi(pu[c]) + bf_hi(qu[c]);
        }
    }
    #pragma unroll
    for (int o = 0; o < 64; ++o)
        acc[o] = fmaxf(acc[o], 0.f) + NEG_SLOPE * fminf(acc[o], 0.f);

    // pack to bf16, swizzled LDS store: row l, chunk c at (c ^ (l&7))
    unsigned up[32];
    #pragma unroll
    for (int i = 0; i < 32; ++i)
        up[i] = cvtpk_bf16(acc[2 * i], acc[2 * i + 1]);
    const int rowbase = w * 512 + l * 8;
    #pragma unroll
    for (int c = 0; c < 8; ++c)
        H[rowbase + (c ^ (l & 7))] = make_uint4(up[4*c], up[4*c+1], up[4*c+2], up[4*c+3]);

    __syncthreads();   // ds_write -> ds_read ordering (single barrier)

    // ---- phase 2: 4 edge-tiles of 16 ----
    const floatx4 z4 = {0.f, 0.f, 0.f, 0.f};
    #pragma unroll
    for (int c = 0; c < 4; ++c) {
        int brow = 16 * c + (l & 15);
        int bbase = w * 512 + brow * 8;
        short8 bf0 = *(const short8*)&H[bbase + ((    (l >> 4)) ^ (l & 7))];  // kk=0
        short8 bf1 = *(const short8*)&H[bbase + ((4 + (l >> 4)) ^ (l & 7))];  // kk=1
        floatx4 accA = __builtin_amdgcn_mfma_f32_16x16x32_bf16(afrag[0][0], bf0, z4, 0, 0, 0);
        accA = __builtin_amdgcn_mfma_f32_16x16x32_bf16(afrag[0][1], bf1, accA, 0, 0, 0);
        floatx4 accB = __builtin_amdgcn_mfma_f32_16x16x32_bf16(afrag[1][0], bf0, z4, 0, 0, 0);
        accB = __builtin_amdgcn_mfma_f32_16x16x32_bf16(afrag[1][1], bf1, accB, 0, 0, 0);

        float partial = 0.f;
        #pragma unroll
        for (int j = 0; j < 4; ++j) {
            float hA = accA[j] + b20[j];
            hA = fmaxf(hA, 0.f) + NEG_SLOPE * fminf(hA, 0.f);
            float hB = accB[j] + b21[j];
            hB = fmaxf(hB, 0.f) + NEG_SLOPE * fminf(hB, 0.f);
            partial += hA * w30[j] + hB * w31[j];
        }
        partial += __shfl_xor(partial, 16);
        partial += __shfl_xor(partial, 32);
        float att = fmaxf(partial + b3v, 0.f);
        int tgt2 = __shfl(tgt, 16 * c + (l & 15));
        if (l < 16) {
            attv[E0 + 16 * c + l] = att;
            if (att > 0.f) atomicAdd(&deg[tgt2], 1);
        }
    }
}

// ---------------------------------------------------------------------------
// Parallel scan: S1 block-local exclusive scan + block totals,
// S2 scan of 98 totals, S3 add block offsets.
// ---------------------------------------------------------------------------
__global__ __launch_bounds__(1024) void egat_scan1(
        const int* __restrict__ deg, int* __restrict__ offs,
        int* __restrict__ psum) {
    __shared__ int wsum[16];
    int tid = threadIdx.x, lane = tid & 63, w = tid >> 6;
    int i = blockIdx.x * 1024 + tid;
    int v = (i < NNODES) ? deg[i] : 0;
    int incl = v;
    #pragma unroll
    for (int s = 1; s < 64; s <<= 1) {
        int t = __shfl_up(incl, s, 64);
        if (lane >= s) incl += t;
    }
    if (lane == 63) wsum[w] = incl;
    __syncthreads();
    if (w == 0 && lane < 16) {
        int xx = wsum[lane];
        int sc = xx;
        #pragma unroll
        for (int s = 1; s < 16; s <<= 1) {
            int t = __shfl_up(sc, s, 16);
            if ((lane & 15) >= s) sc += t;
        }
        wsum[lane] = sc - xx;
    }
    __syncthreads();
    int excl = wsum[w] + incl - v;
    if (i < NNODES) offs[i] = excl;
    if (tid == 1023) psum[blockIdx.x] = wsum[15] + incl;
}

__global__ void egat_scan2(int* __restrict__ psum, int nb) {
    __shared__ int w0sum;
    int tid = threadIdx.x;            // 128 threads, 2 waves
    int lane = tid & 63, w = tid >> 6;
    int v = (tid < nb) ? psum[tid] : 0;
    int incl = v;
    #pragma unroll
    for (int s = 1; s < 64; s <<= 1) {
        int t = __shfl_up(incl, s, 64);
        if (lane >= s) incl += t;
    }
    if (tid == 63) w0sum = incl;
    __syncthreads();
    int excl = incl - v + ((w == 1) ? w0sum : 0);
    if (tid < nb) psum[tid] = excl;
}

__global__ __launch_bounds__(1024) void egat_scan3(
        int* __restrict__ offs, const int* __restrict__ psum,
        int* __restrict__ cursor) {
    int i = blockIdx.x * 1024 + threadIdx.x;
    if (i < NNODES) {
        int o = offs[i] + psum[blockIdx.x];
        offs[i] = o;
        cursor[i] = o;
    }
}

// ---------------------------------------------------------------------------
// Scatter gated edges into CSR slots as {att, src}.
// ---------------------------------------------------------------------------
__global__ __launch_bounds__(256) void egat_scatter(
        const int* __restrict__ ei, const float* __restrict__ attv,
        int* __restrict__ cursor, float2* __restrict__ csr) {
    int e = blockIdx.x * 256 + threadIdx.x;
    float att = attv[e];
    if (att <= 0.f) return;
    int src = ei[e];
    int tgt = ei[NEDGES + e];
    int pos = atomicAdd(&cursor[tgt], 1);
    csr[pos] = make_float2(att, __int_as_float(src));
}

// ---------------------------------------------------------------------------
// Gather: one wave per node; lanes = channels; no atomics.
// ---------------------------------------------------------------------------
__global__ __launch_bounds__(256) void egat_gather(
        const float2* __restrict__ csr, const int* __restrict__ offs,
        const int* __restrict__ cursor, const float* __restrict__ xsrc,
        const float* __restrict__ xtgt, float* __restrict__ out) {
    int wid = (blockIdx.x * 256 + threadIdx.x) >> 6;
    int lane = threadIdx.x & 63;
    int beg = offs[wid];
    int end = cursor[wid];
    float acc = xtgt[wid * 64 + lane];
    int i = beg;
    for (; i + 3 < end; i += 4) {
        float2 a = csr[i], b = csr[i + 1], c = csr[i + 2], d = csr[i + 3];
        acc += a.x * xsrc[__float_as_int(a.y) * 64 + lane];
        acc += b.x * xsrc[__float_as_int(b.y) * 64 + lane];
        acc += c.x * xsrc[__float_as_int(c.y) * 64 + lane];
        acc += d.x * xsrc[__float_as_int(d.y) * 64 + lane];
    }
    for (; i < end; ++i) {
        float2 a = csr[i];
        acc += a.x * xsrc[__float_as_int(a.y) * 64 + lane];
    }
    out[wid * 64 + lane] = acc;
}

// ---------------------------------------------------------------------------
extern "C" void kernel_launch(void* const* d_in, const int* in_sizes, int n_in,
                              void* d_out, int out_size, void* d_ws, size_t ws_size,
                              hipStream_t stream) {
    const float* x      = (const float*)d_in[0];
    const int*   ei     = (const int*)d_in[1];     // int64 in ref -> int32 here
    const float* eattr  = (const float*)d_in[2];
    const float* W_src  = (const float*)d_in[3];
    const float* b_src  = (const float*)d_in[4];
    const float* W_tgt  = (const float*)d_in[5];
    const float* b_tgt  = (const float*)d_in[6];
    const float* W_edge = (const float*)d_in[7];
    const float* b_edge = (const float*)d_in[8];
    const float* W1     = (const float*)d_in[9];
    const float* b1     = (const float*)d_in[10];
    const float* W2     = (const float*)d_in[11];
    const float* b2     = (const float*)d_in[12];
    const float* W3     = (const float*)d_in[13];
    const float* b3     = (const float*)d_in[14];
    float* out = (float*)d_out;

    // workspace layout
    float* xsrc          = (float*)d_ws;                          // N*64 f32
    float* xtgt          = xsrc + (size_t)NNODES * 64;            // N*64 f32
    unsigned short* ps   = (unsigned short*)(xtgt + (size_t)NNODES * 64); // N*64 bf16
    unsigned short* pt   = ps + (size_t)NNODES * 64;              // N*64 bf16
    float* attv          = (float*)(pt + (size_t)NNODES * 64);    // E f32
    float2* csr          = (float2*)(attv + (size_t)NEDGES);      // E float2
    int* deg             = (int*)(csr + (size_t)NEDGES);          // N
    int* offs            = deg + NNODES;                          // N
    int* cursor          = offs + NNODES;                         // N
    float* Ms            = (float*)(cursor + NNODES);             // 4096
    float* Mt            = Ms + 4096;                             // 4096
    float* w1cp          = Mt + 4096;                             // 512
    float* btot          = w1cp + 512;                            // 64
    int*   psum          = (int*)(btot + 64);                     // 98 (block totals)

    const int NB = (NNODES + 1023) / 1024;   // 98

    egat_precompute<<<1, 256, 0, stream>>>(W1, b1, W_src, b_src, W_tgt, b_tgt,
                                           W_edge, b_edge, Ms, Mt, w1cp, btot);
    egat_zero<<<(NNODES + 255) / 256, 256, 0, stream>>>(deg);
    egat_node<<<2048, 256, 0, stream>>>(x, W_src, b_src, W_tgt, b_tgt, xsrc, xtgt);
    egat_nodeP<<<2048, 256, 0, stream>>>(x, Ms, Mt, btot, ps, pt);
    egat_edge<<<NEDGES / 256, 256, 0, stream>>>(ei, eattr, ps, pt,
                                                w1cp, W2, b2, W3, b3, attv, deg);
    egat_scan1<<<NB, 1024, 0, stream>>>(deg, offs, psum);
    egat_scan2<<<1, 128, 0, stream>>>(psum, NB);
    egat_scan3<<<NB, 1024, 0, stream>>>(offs, psum, cursor);
    egat_scatter<<<NEDGES / 256, 256, 0, stream>>>(ei, attv, cursor, csr);
    egat_gather<<<(NNODES * 64) / 256, 256, 0, stream>>>(csr, offs, cursor,
                                                         xsrc, xtgt, out);
}

// Round 6
// 300.964 us; speedup vs baseline: 9.8403x; 1.4656x over previous
//
#include <hip/hip_runtime.h>
#include <hip/hip_bf16.h>

#define NNODES 100000
#define NEDGES 1600000
#define NEG_SLOPE 0.01f

typedef __attribute__((ext_vector_type(8))) short short8;
typedef __attribute__((ext_vector_type(4))) float floatx4;

// round-to-nearest-even f32 -> bf16 (as ushort)
static __device__ inline unsigned short f2bf(float f) {
    unsigned u = __float_as_uint(f);
    u += 0x7fffu + ((u >> 16) & 1u);
    return (unsigned short)(u >> 16);
}
static __device__ inline float bf_lo(unsigned u) { return __uint_as_float(u << 16); }
static __device__ inline float bf_hi(unsigned u) { return __uint_as_float(u & 0xffff0000u); }
static __device__ inline float bf2f(unsigned short s) { return __uint_as_float((unsigned)s << 16); }

// packed f32x2 -> bf16x2 (single HW instruction)
static __device__ inline unsigned cvtpk_bf16(float a, float b) {
    unsigned r;
    asm("v_cvt_pk_bf16_f32 %0, %1, %2" : "=v"(r) : "v"(a), "v"(b));
    return r;
}

// ---------------------------------------------------------------------------
// Kernel P: algebraic folding.
//   Ms = W1[:,0:64]@W_src, Mt = W1[:,64:128]@W_tgt (64x64)
//   w1cp = W1[:,128:192]@W_edge (64x8)
//   btot = b1 + W1[:,0:64]@b_src + W1[:,64:128]@b_tgt + W1[:,128:192]@b_edge
// ---------------------------------------------------------------------------
__global__ void egat_precompute(const float* __restrict__ W1,
                                const float* __restrict__ b1,
                                const float* __restrict__ Ws,
                                const float* __restrict__ bs,
                                const float* __restrict__ Wt,
                                const float* __restrict__ bt,
                                const float* __restrict__ We,
                                const float* __restrict__ be,
                                float* __restrict__ Ms, float* __restrict__ Mt,
                                float* __restrict__ w1cp, float* __restrict__ btot) {
    int tid = threadIdx.x;
    for (int idx = tid; idx < 4096; idx += 256) {
        int o = idx >> 6, i = idx & 63;
        float s = 0.f, t = 0.f;
        for (int k = 0; k < 64; ++k) {
            s += W1[o * 192 + k]      * Ws[k * 64 + i];
            t += W1[o * 192 + 64 + k] * Wt[k * 64 + i];
        }
        Ms[idx] = s;
        Mt[idx] = t;
    }
    for (int idx = tid; idx < 512; idx += 256) {
        int o = idx >> 3, j = idx & 7;
        float s = 0.f;
        for (int t = 0; t < 64; ++t)
            s += W1[o * 192 + 128 + t] * We[t * 8 + j];
        w1cp[idx] = s;
    }
    if (tid < 64) {
        float s = b1[tid];
        for (int k = 0; k < 64; ++k) {
            s += W1[tid * 192 + k]       * bs[k];
            s += W1[tid * 192 + 64 + k]  * bt[k];
        }
        for (int t = 0; t < 64; ++t)
            s += W1[tid * 192 + 128 + t] * be[t];
        btot[tid] = s;
    }
}

__global__ void egat_zero(int* __restrict__ deg) {
    int i = blockIdx.x * 256 + threadIdx.x;
    if (i < NNODES) deg[i] = 0;
}

// ---------------------------------------------------------------------------
// Kernel N (MFMA): one GEMM [N x 64] @ [64 x 256] -> {xsrc(bf16), xtgt(f32),
// ps(bf16,+btot), pt(bf16)}.  Wcat rows 0-63=W_src, 64-127=W_tgt,
// 128-191=Ms, 192-255=Mt, staged bf16 in LDS with XOR chunk swizzle.
// Per wave: 16-node tile; A = x rows (bf16), B = Wcat rows; 16 cc-tiles x 2 kk.
// N = 100000 = 6250 * 16 exactly -> no tail guards.
// ---------------------------------------------------------------------------
__global__ __launch_bounds__(256) void egat_nodeM(
        const float* __restrict__ x,
        const float* __restrict__ Ws, const float* __restrict__ bs,
        const float* __restrict__ Wt, const float* __restrict__ bt,
        const float* __restrict__ Ms, const float* __restrict__ Mt,
        const float* __restrict__ btot,
        unsigned short* __restrict__ xsrcB,   // [N,64] bf16
        float* __restrict__ xtgt,             // [N,64] f32
        unsigned short* __restrict__ ps,      // [N,64] bf16
        unsigned short* __restrict__ pt) {    // [N,64] bf16
    __shared__ uint4 WL[256 * 8];   // 32 KiB
    __shared__ float bias[256];
    const int tid = threadIdx.x;

    {   // stage weights: thread tid handles channel row tid
        int ch = tid;
        const float* srcp = (ch < 64)  ? Ws + ch * 64
                          : (ch < 128) ? Wt + (ch - 64) * 64
                          : (ch < 192) ? Ms + (ch - 128) * 64
                                       : Mt + (ch - 192) * 64;
        bias[ch] = (ch < 64)  ? bs[ch]
                 : (ch < 128) ? bt[ch - 64]
                 : (ch < 192) ? btot[ch - 128]
                              : 0.f;
        #pragma unroll
        for (int c = 0; c < 8; ++c) {
            float4 f0 = *(const float4*)(srcp + c * 8);
            float4 f1 = *(const float4*)(srcp + c * 8 + 4);
            WL[ch * 8 + (c ^ (ch & 7))] =
                make_uint4(cvtpk_bf16(f0.x, f0.y), cvtpk_bf16(f0.z, f0.w),
                           cvtpk_bf16(f1.x, f1.y), cvtpk_bf16(f1.z, f1.w));
        }
    }
    __syncthreads();

    const int w = tid >> 6, l = tid & 63;
    const floatx4 z4 = {0.f, 0.f, 0.f, 0.f};
    const int NT = NNODES / 16;   // 6250 tiles

    for (int tile = blockIdx.x * 4 + w; tile < NT; tile += gridDim.x * 4) {
        const int nodebase = tile * 16;
        // A-frags: lane l -> x[nodebase + (l&15)][32kk + 8(l>>4) + j]
        const float* xp = x + (size_t)(nodebase + (l & 15)) * 64 + 8 * (l >> 4);
        short8 afrag[2];
        #pragma unroll
        for (int kk = 0; kk < 2; ++kk) {
            float4 f0 = *(const float4*)(xp + 32 * kk);
            float4 f1 = *(const float4*)(xp + 32 * kk + 4);
            union { unsigned u[4]; short8 s; } cv;
            cv.u[0] = cvtpk_bf16(f0.x, f0.y);
            cv.u[1] = cvtpk_bf16(f0.z, f0.w);
            cv.u[2] = cvtpk_bf16(f1.x, f1.y);
            cv.u[3] = cvtpk_bf16(f1.z, f1.w);
            afrag[kk] = cv.s;
        }
        #pragma unroll
        for (int cc = 0; cc < 16; ++cc) {
            int ch = 16 * cc + (l & 15);
            short8 b0 = *(const short8*)&WL[ch * 8 + (((l >> 4))     ^ (ch & 7))];
            short8 b1 = *(const short8*)&WL[ch * 8 + ((4 + (l >> 4)) ^ (ch & 7))];
            floatx4 acc = __builtin_amdgcn_mfma_f32_16x16x32_bf16(afrag[0], b0, z4, 0, 0, 0);
            acc = __builtin_amdgcn_mfma_f32_16x16x32_bf16(afrag[1], b1, acc, 0, 0, 0);
            float bv = bias[ch];
            #pragma unroll
            for (int r = 0; r < 4; ++r) {
                int node = nodebase + (l >> 4) * 4 + r;
                float v = acc[r] + bv;
                if (cc < 4)
                    xsrcB[(size_t)node * 64 + ch] = f2bf(v);
                else if (cc < 8)
                    xtgt[(size_t)node * 64 + (ch - 64)] = v;
                else if (cc < 12)
                    ps[(size_t)node * 64 + (ch - 128)] = f2bf(v);
                else
                    pt[(size_t)node * 64 + (ch - 192)] = f2bf(v);
            }
        }
    }
}

// ---------------------------------------------------------------------------
// Kernel E: per-edge attention; MFMA layer-2; wave-independent (no block
// barrier — each wave only touches its own 8 KiB H region).
// ---------------------------------------------------------------------------
__global__ __launch_bounds__(256) void egat_edge(
        const int* __restrict__ ei,                 // [2, E] int32
        const float* __restrict__ eattr,            // [E, 8]
        const unsigned short* __restrict__ ps,      // [N, 64] bf16
        const unsigned short* __restrict__ pt,      // [N, 64] bf16
        const float* __restrict__ w1cp,             // [64, 8]
        const float* __restrict__ W2,               // [32, 64]
        const float* __restrict__ b2,               // [32]
        const float* __restrict__ W3,               // [1, 32]
        const float* __restrict__ b3,               // [1]
        float* __restrict__ attv,                   // [E]
        int* __restrict__ deg) {                    // [N]
    __shared__ uint4 H[4 * 64 * 8];   // 32 KiB: per-wave [64 rows][8 chunks]
    const int tid = threadIdx.x;
    const int w = tid >> 6, l = tid & 63;
    const int e = blockIdx.x * 256 + tid;
    const int E0 = blockIdx.x * 256 + w * 64;

    int src = ei[e];
    int tgt = ei[NEDGES + e];

    // issue the two random gathers as early as possible
    const uint4* pr = (const uint4*)(ps + (size_t)src * 64);
    const uint4* qr = (const uint4*)(pt + (size_t)tgt * 64);
    uint4 P[4], Q[4];
    #pragma unroll
    for (int r = 0; r < 4; ++r) { P[r] = pr[r]; Q[r] = qr[r]; }
    uint4 P2[4], Q2[4];
    #pragma unroll
    for (int r = 0; r < 4; ++r) { P2[r] = pr[4 + r]; Q2[r] = qr[4 + r]; }

    const float4* eav = (const float4*)(eattr + (long long)e * 8);
    float4 ea0 = eav[0], ea1 = eav[1];
    float ea[8] = {ea0.x, ea0.y, ea0.z, ea0.w, ea1.x, ea1.y, ea1.z, ea1.w};

    // ---- A-frags from W2 (wave-uniform scalar-ish loads) ----
    short8 afrag[2][2];
    #pragma unroll
    for (int rp = 0; rp < 2; ++rp) {
        #pragma unroll
        for (int kk = 0; kk < 2; ++kk) {
            const float* wp = W2 + (16 * rp + (l & 15)) * 64 + 32 * kk + 8 * (l >> 4);
            float4 f0 = *(const float4*)wp;
            float4 f1 = *(const float4*)(wp + 4);
            union { unsigned u[4]; short8 s; } cv;
            cv.u[0] = cvtpk_bf16(f0.x, f0.y);
            cv.u[1] = cvtpk_bf16(f0.z, f0.w);
            cv.u[2] = cvtpk_bf16(f1.x, f1.y);
            cv.u[3] = cvtpk_bf16(f1.z, f1.w);
            afrag[rp][kk] = cv.s;
        }
    }
    const int g = l >> 4;
    float w30[4], w31[4], b20[4], b21[4];
    #pragma unroll
    for (int j = 0; j < 4; ++j) {
        w30[j] = W3[4 * g + j];  w31[j] = W3[16 + 4 * g + j];
        b20[j] = b2[4 * g + j];  b21[j] = b2[16 + 4 * g + j];
    }
    const float b3v = b3[0];

    // ---- phase 1: h1 = lrelu(ps[src] + pt[tgt] + w1cp@ea) ----
    float acc[64];
    #pragma unroll
    for (int o = 0; o < 64; ++o) {
        float s = 0.f;
        #pragma unroll
        for (int j = 0; j < 8; ++j)
            s += w1cp[o * 8 + j] * ea[j];
        acc[o] = s;
    }
    #pragma unroll
    for (int r = 0; r < 8; ++r) {
        uint4 p = (r < 4) ? P[r] : P2[r - 4];
        uint4 q = (r < 4) ? Q[r] : Q2[r - 4];
        unsigned pu[4] = {p.x, p.y, p.z, p.w};
        unsigned qu[4] = {q.x, q.y, q.z, q.w};
        #pragma unroll
        for (int c = 0; c < 4; ++c) {
            acc[r * 8 + 2 * c]     += bf_lo(pu[c]) + bf_lo(qu[c]);
            acc[r * 8 + 2 * c + 1] += bf_hi(pu[c]) + bf_hi(qu[c]);
        }
    }
    #pragma unroll
    for (int o = 0; o < 64; ++o)
        acc[o] = fmaxf(acc[o], 0.f) + NEG_SLOPE * fminf(acc[o], 0.f);

    // pack to bf16, swizzled LDS store: row l, chunk c at (c ^ (l&7))
    unsigned up[32];
    #pragma unroll
    for (int i = 0; i < 32; ++i)
        up[i] = cvtpk_bf16(acc[2 * i], acc[2 * i + 1]);
    const int rowbase = w * 512 + l * 8;
    #pragma unroll
    for (int c = 0; c < 8; ++c)
        H[rowbase + (c ^ (l & 7))] = make_uint4(up[4*c], up[4*c+1], up[4*c+2], up[4*c+3]);

    // wave-local visibility: this wave's ds_writes must complete before its
    // own ds_reads (no cross-wave sharing -> no block barrier needed)
    asm volatile("s_waitcnt lgkmcnt(0)" ::: "memory");
    __builtin_amdgcn_sched_barrier(0);

    // ---- phase 2: 4 edge-tiles of 16 ----
    const floatx4 z4 = {0.f, 0.f, 0.f, 0.f};
    #pragma unroll
    for (int c = 0; c < 4; ++c) {
        int brow = 16 * c + (l & 15);
        int bbase = w * 512 + brow * 8;
        short8 bf0 = *(const short8*)&H[bbase + ((    (l >> 4)) ^ (l & 7))];
        short8 bf1 = *(const short8*)&H[bbase + ((4 + (l >> 4)) ^ (l & 7))];
        floatx4 accA = __builtin_amdgcn_mfma_f32_16x16x32_bf16(afrag[0][0], bf0, z4, 0, 0, 0);
        accA = __builtin_amdgcn_mfma_f32_16x16x32_bf16(afrag[0][1], bf1, accA, 0, 0, 0);
        floatx4 accB = __builtin_amdgcn_mfma_f32_16x16x32_bf16(afrag[1][0], bf0, z4, 0, 0, 0);
        accB = __builtin_amdgcn_mfma_f32_16x16x32_bf16(afrag[1][1], bf1, accB, 0, 0, 0);

        float partial = 0.f;
        #pragma unroll
        for (int j = 0; j < 4; ++j) {
            float hA = accA[j] + b20[j];
            hA = fmaxf(hA, 0.f) + NEG_SLOPE * fminf(hA, 0.f);
            float hB = accB[j] + b21[j];
            hB = fmaxf(hB, 0.f) + NEG_SLOPE * fminf(hB, 0.f);
            partial += hA * w30[j] + hB * w31[j];
        }
        partial += __shfl_xor(partial, 16);
        partial += __shfl_xor(partial, 32);
        float att = fmaxf(partial + b3v, 0.f);
        int tgt2 = __shfl(tgt, 16 * c + (l & 15));
        if (l < 16) {
            attv[E0 + 16 * c + l] = att;
            if (att > 0.f) atomicAdd(&deg[tgt2], 1);
        }
    }
}

// ---------------------------------------------------------------------------
// Parallel scan: S1 block-local + totals, S2 totals scan, S3 add offsets.
// ---------------------------------------------------------------------------
__global__ __launch_bounds__(1024) void egat_scan1(
        const int* __restrict__ deg, int* __restrict__ offs,
        int* __restrict__ psum) {
    __shared__ int wsum[16];
    int tid = threadIdx.x, lane = tid & 63, w = tid >> 6;
    int i = blockIdx.x * 1024 + tid;
    int v = (i < NNODES) ? deg[i] : 0;
    int incl = v;
    #pragma unroll
    for (int s = 1; s < 64; s <<= 1) {
        int t = __shfl_up(incl, s, 64);
        if (lane >= s) incl += t;
    }
    if (lane == 63) wsum[w] = incl;
    __syncthreads();
    if (w == 0 && lane < 16) {
        int xx = wsum[lane];
        int sc = xx;
        #pragma unroll
        for (int s = 1; s < 16; s <<= 1) {
            int t = __shfl_up(sc, s, 16);
            if ((lane & 15) >= s) sc += t;
        }
        wsum[lane] = sc - xx;
    }
    __syncthreads();
    int excl = wsum[w] + incl - v;
    if (i < NNODES) offs[i] = excl;
    if (tid == 1023) psum[blockIdx.x] = wsum[15] + incl;
}

__global__ void egat_scan2(int* __restrict__ psum, int nb) {
    __shared__ int w0sum;
    int tid = threadIdx.x;            // 128 threads, 2 waves
    int lane = tid & 63, w = tid >> 6;
    int v = (tid < nb) ? psum[tid] : 0;
    int incl = v;
    #pragma unroll
    for (int s = 1; s < 64; s <<= 1) {
        int t = __shfl_up(incl, s, 64);
        if (lane >= s) incl += t;
    }
    if (tid == 63) w0sum = incl;
    __syncthreads();
    int excl = incl - v + ((w == 1) ? w0sum : 0);
    if (tid < nb) psum[tid] = excl;
}

__global__ __launch_bounds__(1024) void egat_scan3(
        int* __restrict__ offs, const int* __restrict__ psum,
        int* __restrict__ cursor) {
    int i = blockIdx.x * 1024 + threadIdx.x;
    if (i < NNODES) {
        int o = offs[i] + psum[blockIdx.x];
        offs[i] = o;
        cursor[i] = o;
    }
}

// ---------------------------------------------------------------------------
// Scatter gated edges into CSR slots as {att, src}.
// ---------------------------------------------------------------------------
__global__ __launch_bounds__(256) void egat_scatter(
        const int* __restrict__ ei, const float* __restrict__ attv,
        int* __restrict__ cursor, float2* __restrict__ csr) {
    int e = blockIdx.x * 256 + threadIdx.x;
    float att = attv[e];
    if (att <= 0.f) return;
    int src = ei[e];
    int tgt = ei[NEDGES + e];
    int pos = atomicAdd(&cursor[tgt], 1);
    csr[pos] = make_float2(att, __int_as_float(src));
}

// ---------------------------------------------------------------------------
// Gather: one wave per node; lanes = channels; bf16 xsrc rows (128B).
// ---------------------------------------------------------------------------
__global__ __launch_bounds__(256) void egat_gather(
        const float2* __restrict__ csr, const int* __restrict__ offs,
        const int* __restrict__ cursor,
        const unsigned short* __restrict__ xsrcB,
        const float* __restrict__ xtgt, float* __restrict__ out) {
    int wid = (blockIdx.x * 256 + threadIdx.x) >> 6;
    int lane = threadIdx.x & 63;
    int beg = offs[wid];
    int end = cursor[wid];
    float acc = xtgt[wid * 64 + lane];
    int i = beg;
    for (; i + 3 < end; i += 4) {
        float2 a = csr[i], b = csr[i + 1], c = csr[i + 2], d = csr[i + 3];
        acc += a.x * bf2f(xsrcB[(size_t)__float_as_int(a.y) * 64 + lane]);
        acc += b.x * bf2f(xsrcB[(size_t)__float_as_int(b.y) * 64 + lane]);
        acc += c.x * bf2f(xsrcB[(size_t)__float_as_int(c.y) * 64 + lane]);
        acc += d.x * bf2f(xsrcB[(size_t)__float_as_int(d.y) * 64 + lane]);
    }
    for (; i < end; ++i) {
        float2 a = csr[i];
        acc += a.x * bf2f(xsrcB[(size_t)__float_as_int(a.y) * 64 + lane]);
    }
    out[wid * 64 + lane] = acc;
}

// ---------------------------------------------------------------------------
extern "C" void kernel_launch(void* const* d_in, const int* in_sizes, int n_in,
                              void* d_out, int out_size, void* d_ws, size_t ws_size,
                              hipStream_t stream) {
    const float* x      = (const float*)d_in[0];
    const int*   ei     = (const int*)d_in[1];     // int64 in ref -> int32 here
    const float* eattr  = (const float*)d_in[2];
    const float* W_src  = (const float*)d_in[3];
    const float* b_src  = (const float*)d_in[4];
    const float* W_tgt  = (const float*)d_in[5];
    const float* b_tgt  = (const float*)d_in[6];
    const float* W_edge = (const float*)d_in[7];
    const float* b_edge = (const float*)d_in[8];
    const float* W1     = (const float*)d_in[9];
    const float* b1     = (const float*)d_in[10];
    const float* W2     = (const float*)d_in[11];
    const float* b2     = (const float*)d_in[12];
    const float* W3     = (const float*)d_in[13];
    const float* b3     = (const float*)d_in[14];
    float* out = (float*)d_out;

    const size_t N64 = (size_t)NNODES * 64;

    // workspace layout
    float* xtgt          = (float*)d_ws;                          // N*64 f32
    unsigned short* xsrcB = (unsigned short*)(xtgt + N64);        // N*64 bf16
    unsigned short* ps   = xsrcB + N64;                           // N*64 bf16
    unsigned short* pt   = ps + N64;                              // N*64 bf16
    float* attv          = (float*)(pt + N64);                    // E f32
    float2* csr          = (float2*)(attv + (size_t)NEDGES);      // E float2
    int* deg             = (int*)(csr + (size_t)NEDGES);          // N
    int* offs            = deg + NNODES;                          // N
    int* cursor          = offs + NNODES;                         // N
    float* Ms            = (float*)(cursor + NNODES);             // 4096
    float* Mt            = Ms + 4096;                             // 4096
    float* w1cp          = Mt + 4096;                             // 512
    float* btot          = w1cp + 512;                            // 64
    int*   psum          = (int*)(btot + 64);                     // 98

    const int NB = (NNODES + 1023) / 1024;   // 98

    egat_precompute<<<1, 256, 0, stream>>>(W1, b1, W_src, b_src, W_tgt, b_tgt,
                                           W_edge, b_edge, Ms, Mt, w1cp, btot);
    egat_zero<<<(NNODES + 255) / 256, 256, 0, stream>>>(deg);
    egat_nodeM<<<640, 256, 0, stream>>>(x, W_src, b_src, W_tgt, b_tgt,
                                        Ms, Mt, btot, xsrcB, xtgt, ps, pt);
    egat_edge<<<NEDGES / 256, 256, 0, stream>>>(ei, eattr, ps, pt,
                                                w1cp, W2, b2, W3, b3, attv, deg);
    egat_scan1<<<NB, 1024, 0, stream>>>(deg, offs, psum);
    egat_scan2<<<1, 128, 0, stream>>>(psum, NB);
    egat_scan3<<<NB, 1024, 0, stream>>>(offs, psum, cursor);
    egat_scatter<<<NEDGES / 256, 256, 0, stream>>>(ei, attv, cursor, csr);
    egat_gather<<<(NNODES * 64) / 256, 256, 0, stream>>>(csr, offs, cursor,
                                                         xsrcB, xtgt, out);
}

// Round 7
// 261.820 us; speedup vs baseline: 11.3115x; 1.1495x over previous
//
#include <hip/hip_runtime.h>
#include <hip/hip_bf16.h>

#define NNODES 100000
#define NEDGES 1600000
#define NEG_SLOPE 0.01f

typedef __attribute__((ext_vector_type(8))) short short8;
typedef __attribute__((ext_vector_type(4))) float floatx4;

// round-to-nearest-even f32 -> bf16 (as ushort)
static __device__ inline unsigned short f2bf(float f) {
    unsigned u = __float_as_uint(f);
    u += 0x7fffu + ((u >> 16) & 1u);
    return (unsigned short)(u >> 16);
}
static __device__ inline float bf2f(unsigned short s) { return __uint_as_float((unsigned)s << 16); }

// packed f32x2 -> bf16x2 (single HW instruction)
static __device__ inline unsigned cvtpk_bf16(float a, float b) {
    unsigned r;
    asm("v_cvt_pk_bf16_f32 %0, %1, %2" : "=v"(r) : "v"(a), "v"(b));
    return r;
}
// single f32 -> fp8 e4m3 (OCP) in low byte
static __device__ inline unsigned char f2fp8(float v) {
    return (unsigned char)(__builtin_amdgcn_cvt_pk_fp8_f32(v, v, 0u, false) & 0xffu);
}

// ---------------------------------------------------------------------------
// Kernel P: algebraic folding.
//   Ms = W1[:,0:64]@W_src, Mt = W1[:,64:128]@W_tgt (64x64)
//   w1cp = W1[:,128:192]@W_edge (64x8)
//   btot = b1 + W1[:,0:64]@b_src + W1[:,64:128]@b_tgt + W1[:,128:192]@b_edge
// ---------------------------------------------------------------------------
__global__ void egat_precompute(const float* __restrict__ W1,
                                const float* __restrict__ b1,
                                const float* __restrict__ Ws,
                                const float* __restrict__ bs,
                                const float* __restrict__ Wt,
                                const float* __restrict__ bt,
                                const float* __restrict__ We,
                                const float* __restrict__ be,
                                float* __restrict__ Ms, float* __restrict__ Mt,
                                float* __restrict__ w1cp, float* __restrict__ btot) {
    int tid = threadIdx.x;
    for (int idx = tid; idx < 4096; idx += 256) {
        int o = idx >> 6, i = idx & 63;
        float s = 0.f, t = 0.f;
        for (int k = 0; k < 64; ++k) {
            s += W1[o * 192 + k]      * Ws[k * 64 + i];
            t += W1[o * 192 + 64 + k] * Wt[k * 64 + i];
        }
        Ms[idx] = s;
        Mt[idx] = t;
    }
    for (int idx = tid; idx < 512; idx += 256) {
        int o = idx >> 3, j = idx & 7;
        float s = 0.f;
        for (int t = 0; t < 64; ++t)
            s += W1[o * 192 + 128 + t] * We[t * 8 + j];
        w1cp[idx] = s;
    }
    if (tid < 64) {
        float s = b1[tid];
        for (int k = 0; k < 64; ++k) {
            s += W1[tid * 192 + k]       * bs[k];
            s += W1[tid * 192 + 64 + k]  * bt[k];
        }
        for (int t = 0; t < 64; ++t)
            s += W1[tid * 192 + 128 + t] * be[t];
        btot[tid] = s;
    }
}

__global__ void egat_zero(int* __restrict__ deg) {
    int i = blockIdx.x * 256 + threadIdx.x;
    if (i < NNODES) deg[i] = 0;
}

// ---------------------------------------------------------------------------
// Kernel N (MFMA): one GEMM [N x 64] @ [64 x 256] -> {xsrc(bf16), xtgt(f32),
// ps(fp8,+btot), pt(fp8)}.  Wcat rows 0-63=W_src, 64-127=W_tgt, 128-191=Ms,
// 192-255=Mt; staged bf16 in LDS with XOR chunk swizzle.
// ---------------------------------------------------------------------------
__global__ __launch_bounds__(256) void egat_nodeM(
        const float* __restrict__ x,
        const float* __restrict__ Ws, const float* __restrict__ bs,
        const float* __restrict__ Wt, const float* __restrict__ bt,
        const float* __restrict__ Ms, const float* __restrict__ Mt,
        const float* __restrict__ btot,
        unsigned short* __restrict__ xsrcB,    // [N,64] bf16
        float* __restrict__ xtgt,              // [N,64] f32
        unsigned char* __restrict__ ps8,       // [N,64] fp8
        unsigned char* __restrict__ pt8) {     // [N,64] fp8
    __shared__ uint4 WL[256 * 8];   // 32 KiB
    __shared__ float bias[256];
    const int tid = threadIdx.x;

    {   // stage weights: thread tid handles channel row tid
        int ch = tid;
        const float* srcp = (ch < 64)  ? Ws + ch * 64
                          : (ch < 128) ? Wt + (ch - 64) * 64
                          : (ch < 192) ? Ms + (ch - 128) * 64
                                       : Mt + (ch - 192) * 64;
        bias[ch] = (ch < 64)  ? bs[ch]
                 : (ch < 128) ? bt[ch - 64]
                 : (ch < 192) ? btot[ch - 128]
                              : 0.f;
        #pragma unroll
        for (int c = 0; c < 8; ++c) {
            float4 f0 = *(const float4*)(srcp + c * 8);
            float4 f1 = *(const float4*)(srcp + c * 8 + 4);
            WL[ch * 8 + (c ^ (ch & 7))] =
                make_uint4(cvtpk_bf16(f0.x, f0.y), cvtpk_bf16(f0.z, f0.w),
                           cvtpk_bf16(f1.x, f1.y), cvtpk_bf16(f1.z, f1.w));
        }
    }
    __syncthreads();

    const int w = tid >> 6, l = tid & 63;
    const floatx4 z4 = {0.f, 0.f, 0.f, 0.f};
    const int NT = NNODES / 16;   // 6250 tiles

    for (int tile = blockIdx.x * 4 + w; tile < NT; tile += gridDim.x * 4) {
        const int nodebase = tile * 16;
        const float* xp = x + (size_t)(nodebase + (l & 15)) * 64 + 8 * (l >> 4);
        short8 afrag[2];
        #pragma unroll
        for (int kk = 0; kk < 2; ++kk) {
            float4 f0 = *(const float4*)(xp + 32 * kk);
            float4 f1 = *(const float4*)(xp + 32 * kk + 4);
            union { unsigned u[4]; short8 s; } cv;
            cv.u[0] = cvtpk_bf16(f0.x, f0.y);
            cv.u[1] = cvtpk_bf16(f0.z, f0.w);
            cv.u[2] = cvtpk_bf16(f1.x, f1.y);
            cv.u[3] = cvtpk_bf16(f1.z, f1.w);
            afrag[kk] = cv.s;
        }
        #pragma unroll
        for (int cc = 0; cc < 16; ++cc) {
            int ch = 16 * cc + (l & 15);
            short8 b0 = *(const short8*)&WL[ch * 8 + (((l >> 4))     ^ (ch & 7))];
            short8 b1 = *(const short8*)&WL[ch * 8 + ((4 + (l >> 4)) ^ (ch & 7))];
            floatx4 acc = __builtin_amdgcn_mfma_f32_16x16x32_bf16(afrag[0], b0, z4, 0, 0, 0);
            acc = __builtin_amdgcn_mfma_f32_16x16x32_bf16(afrag[1], b1, acc, 0, 0, 0);
            float bv = bias[ch];
            #pragma unroll
            for (int r = 0; r < 4; ++r) {
                int node = nodebase + (l >> 4) * 4 + r;
                float v = acc[r] + bv;
                if (cc < 4)
                    xsrcB[(size_t)node * 64 + ch] = f2bf(v);
                else if (cc < 8)
                    xtgt[(size_t)node * 64 + (ch - 64)] = v;
                else if (cc < 12)
                    ps8[(size_t)node * 64 + (ch - 128)] = f2fp8(v);
                else
                    pt8[(size_t)node * 64 + (ch - 192)] = f2fp8(v);
            }
        }
    }
}

// ---------------------------------------------------------------------------
// Kernel E: per-edge attention; fp8 ps/pt gathers (64B rows); MFMA layer-2;
// wave-independent (no block barrier).
// ---------------------------------------------------------------------------
__global__ __launch_bounds__(256) void egat_edge(
        const int* __restrict__ ei,                 // [2, E] int32
        const float* __restrict__ eattr,            // [E, 8]
        const unsigned char* __restrict__ ps8,      // [N, 64] fp8
        const unsigned char* __restrict__ pt8,      // [N, 64] fp8
        const float* __restrict__ w1cp,             // [64, 8]
        const float* __restrict__ W2,               // [32, 64]
        const float* __restrict__ b2,               // [32]
        const float* __restrict__ W3,               // [1, 32]
        const float* __restrict__ b3,               // [1]
        float* __restrict__ attv,                   // [E]
        int* __restrict__ deg) {                    // [N]
    __shared__ uint4 H[4 * 64 * 8];   // 32 KiB: per-wave [64 rows][8 chunks]
    const int tid = threadIdx.x;
    const int w = tid >> 6, l = tid & 63;
    const int e = blockIdx.x * 256 + tid;
    const int E0 = blockIdx.x * 256 + w * 64;

    int src = ei[e];
    int tgt = ei[NEDGES + e];

    // issue the two random 64B-row gathers as early as possible
    const uint4* pr = (const uint4*)(ps8 + (size_t)src * 64);
    const uint4* qr = (const uint4*)(pt8 + (size_t)tgt * 64);
    uint4 P[4], Q[4];
    #pragma unroll
    for (int r = 0; r < 4; ++r) { P[r] = pr[r]; Q[r] = qr[r]; }

    const float4* eav = (const float4*)(eattr + (long long)e * 8);
    float4 ea0 = eav[0], ea1 = eav[1];
    float ea[8] = {ea0.x, ea0.y, ea0.z, ea0.w, ea1.x, ea1.y, ea1.z, ea1.w};

    // ---- A-frags from W2 ----
    short8 afrag[2][2];
    #pragma unroll
    for (int rp = 0; rp < 2; ++rp) {
        #pragma unroll
        for (int kk = 0; kk < 2; ++kk) {
            const float* wp = W2 + (16 * rp + (l & 15)) * 64 + 32 * kk + 8 * (l >> 4);
            float4 f0 = *(const float4*)wp;
            float4 f1 = *(const float4*)(wp + 4);
            union { unsigned u[4]; short8 s; } cv;
            cv.u[0] = cvtpk_bf16(f0.x, f0.y);
            cv.u[1] = cvtpk_bf16(f0.z, f0.w);
            cv.u[2] = cvtpk_bf16(f1.x, f1.y);
            cv.u[3] = cvtpk_bf16(f1.z, f1.w);
            afrag[rp][kk] = cv.s;
        }
    }
    const int g = l >> 4;
    float w30[4], w31[4], b20[4], b21[4];
    #pragma unroll
    for (int j = 0; j < 4; ++j) {
        w30[j] = W3[4 * g + j];  w31[j] = W3[16 + 4 * g + j];
        b20[j] = b2[4 * g + j];  b21[j] = b2[16 + 4 * g + j];
    }
    const float b3v = b3[0];

    // ---- phase 1: h1 = lrelu(ps[src] + pt[tgt] + w1cp@ea) ----
    float acc[64];
    #pragma unroll
    for (int o = 0; o < 64; ++o) {
        float s = 0.f;
        #pragma unroll
        for (int j = 0; j < 8; ++j)
            s += w1cp[o * 8 + j] * ea[j];
        acc[o] = s;
    }
    #pragma unroll
    for (int r = 0; r < 4; ++r) {
        unsigned pu[4] = {P[r].x, P[r].y, P[r].z, P[r].w};
        unsigned qu[4] = {Q[r].x, Q[r].y, Q[r].z, Q[r].w};
        #pragma unroll
        for (int c = 0; c < 4; ++c) {
            auto plo = __builtin_amdgcn_cvt_pk_f32_fp8(pu[c], false);
            auto phi = __builtin_amdgcn_cvt_pk_f32_fp8(pu[c], true);
            auto qlo = __builtin_amdgcn_cvt_pk_f32_fp8(qu[c], false);
            auto qhi = __builtin_amdgcn_cvt_pk_f32_fp8(qu[c], true);
            int o = 16 * r + 4 * c;
            acc[o + 0] += plo[0] + qlo[0];
            acc[o + 1] += plo[1] + qlo[1];
            acc[o + 2] += phi[0] + qhi[0];
            acc[o + 3] += phi[1] + qhi[1];
        }
    }
    #pragma unroll
    for (int o = 0; o < 64; ++o)
        acc[o] = fmaxf(acc[o], 0.f) + NEG_SLOPE * fminf(acc[o], 0.f);

    // pack to bf16, swizzled LDS store: row l, chunk c at (c ^ (l&7))
    unsigned up[32];
    #pragma unroll
    for (int i = 0; i < 32; ++i)
        up[i] = cvtpk_bf16(acc[2 * i], acc[2 * i + 1]);
    const int rowbase = w * 512 + l * 8;
    #pragma unroll
    for (int c = 0; c < 8; ++c)
        H[rowbase + (c ^ (l & 7))] = make_uint4(up[4*c], up[4*c+1], up[4*c+2], up[4*c+3]);

    // wave-local visibility only (each wave uses its own 8 KiB H region)
    asm volatile("s_waitcnt lgkmcnt(0)" ::: "memory");
    __builtin_amdgcn_sched_barrier(0);

    // ---- phase 2: 4 edge-tiles of 16 ----
    const floatx4 z4 = {0.f, 0.f, 0.f, 0.f};
    #pragma unroll
    for (int c = 0; c < 4; ++c) {
        int brow = 16 * c + (l & 15);
        int bbase = w * 512 + brow * 8;
        short8 bf0 = *(const short8*)&H[bbase + ((    (l >> 4)) ^ (l & 7))];
        short8 bf1 = *(const short8*)&H[bbase + ((4 + (l >> 4)) ^ (l & 7))];
        floatx4 accA = __builtin_amdgcn_mfma_f32_16x16x32_bf16(afrag[0][0], bf0, z4, 0, 0, 0);
        accA = __builtin_amdgcn_mfma_f32_16x16x32_bf16(afrag[0][1], bf1, accA, 0, 0, 0);
        floatx4 accB = __builtin_amdgcn_mfma_f32_16x16x32_bf16(afrag[1][0], bf0, z4, 0, 0, 0);
        accB = __builtin_amdgcn_mfma_f32_16x16x32_bf16(afrag[1][1], bf1, accB, 0, 0, 0);

        float partial = 0.f;
        #pragma unroll
        for (int j = 0; j < 4; ++j) {
            float hA = accA[j] + b20[j];
            hA = fmaxf(hA, 0.f) + NEG_SLOPE * fminf(hA, 0.f);
            float hB = accB[j] + b21[j];
            hB = fmaxf(hB, 0.f) + NEG_SLOPE * fminf(hB, 0.f);
            partial += hA * w30[j] + hB * w31[j];
        }
        partial += __shfl_xor(partial, 16);
        partial += __shfl_xor(partial, 32);
        float att = fmaxf(partial + b3v, 0.f);
        int tgt2 = __shfl(tgt, 16 * c + (l & 15));
        if (l < 16) {
            attv[E0 + 16 * c + l] = att;
            if (att > 0.f) atomicAdd(&deg[tgt2], 1);
        }
    }
}

// ---------------------------------------------------------------------------
// Parallel scan: S1 block-local + totals, S2 totals scan, S3 add offsets.
// ---------------------------------------------------------------------------
__global__ __launch_bounds__(1024) void egat_scan1(
        const int* __restrict__ deg, int* __restrict__ offs,
        int* __restrict__ psum) {
    __shared__ int wsum[16];
    int tid = threadIdx.x, lane = tid & 63, w = tid >> 6;
    int i = blockIdx.x * 1024 + tid;
    int v = (i < NNODES) ? deg[i] : 0;
    int incl = v;
    #pragma unroll
    for (int s = 1; s < 64; s <<= 1) {
        int t = __shfl_up(incl, s, 64);
        if (lane >= s) incl += t;
    }
    if (lane == 63) wsum[w] = incl;
    __syncthreads();
    if (w == 0 && lane < 16) {
        int xx = wsum[lane];
        int sc = xx;
        #pragma unroll
        for (int s = 1; s < 16; s <<= 1) {
            int t = __shfl_up(sc, s, 16);
            if ((lane & 15) >= s) sc += t;
        }
        wsum[lane] = sc - xx;
    }
    __syncthreads();
    int excl = wsum[w] + incl - v;
    if (i < NNODES) offs[i] = excl;
    if (tid == 1023) psum[blockIdx.x] = wsum[15] + incl;
}

__global__ void egat_scan2(int* __restrict__ psum, int nb) {
    __shared__ int w0sum;
    int tid = threadIdx.x;            // 128 threads, 2 waves
    int lane = tid & 63, w = tid >> 6;
    int v = (tid < nb) ? psum[tid] : 0;
    int incl = v;
    #pragma unroll
    for (int s = 1; s < 64; s <<= 1) {
        int t = __shfl_up(incl, s, 64);
        if (lane >= s) incl += t;
    }
    if (tid == 63) w0sum = incl;
    __syncthreads();
    int excl = incl - v + ((w == 1) ? w0sum : 0);
    if (tid < nb) psum[tid] = excl;
}

__global__ __launch_bounds__(1024) void egat_scan3(
        int* __restrict__ offs, const int* __restrict__ psum,
        int* __restrict__ cursor) {
    int i = blockIdx.x * 1024 + threadIdx.x;
    if (i < NNODES) {
        int o = offs[i] + psum[blockIdx.x];
        offs[i] = o;
        cursor[i] = o;
    }
}

// ---------------------------------------------------------------------------
// Scatter gated edges into CSR slots as {att, src}.
// ---------------------------------------------------------------------------
__global__ __launch_bounds__(256) void egat_scatter(
        const int* __restrict__ ei, const float* __restrict__ attv,
        int* __restrict__ cursor, float2* __restrict__ csr) {
    int e = blockIdx.x * 256 + threadIdx.x;
    float att = attv[e];
    if (att <= 0.f) return;
    int src = ei[e];
    int tgt = ei[NEDGES + e];
    int pos = atomicAdd(&cursor[tgt], 1);
    csr[pos] = make_float2(att, __int_as_float(src));
}

// ---------------------------------------------------------------------------
// Gather: one wave per node; lanes = channels; bf16 xsrc rows (128B).
// ---------------------------------------------------------------------------
__global__ __launch_bounds__(256) void egat_gather(
        const float2* __restrict__ csr, const int* __restrict__ offs,
        const int* __restrict__ cursor,
        const unsigned short* __restrict__ xsrcB,
        const float* __restrict__ xtgt, float* __restrict__ out) {
    int wid = (blockIdx.x * 256 + threadIdx.x) >> 6;
    int lane = threadIdx.x & 63;
    int beg = offs[wid];
    int end = cursor[wid];
    float acc = xtgt[wid * 64 + lane];
    int i = beg;
    for (; i + 3 < end; i += 4) {
        float2 a = csr[i], b = csr[i + 1], c = csr[i + 2], d = csr[i + 3];
        acc += a.x * bf2f(xsrcB[(size_t)__float_as_int(a.y) * 64 + lane]);
        acc += b.x * bf2f(xsrcB[(size_t)__float_as_int(b.y) * 64 + lane]);
        acc += c.x * bf2f(xsrcB[(size_t)__float_as_int(c.y) * 64 + lane]);
        acc += d.x * bf2f(xsrcB[(size_t)__float_as_int(d.y) * 64 + lane]);
    }
    for (; i < end; ++i) {
        float2 a = csr[i];
        acc += a.x * bf2f(xsrcB[(size_t)__float_as_int(a.y) * 64 + lane]);
    }
    out[wid * 64 + lane] = acc;
}

// ---------------------------------------------------------------------------
extern "C" void kernel_launch(void* const* d_in, const int* in_sizes, int n_in,
                              void* d_out, int out_size, void* d_ws, size_t ws_size,
                              hipStream_t stream) {
    const float* x      = (const float*)d_in[0];
    const int*   ei     = (const int*)d_in[1];     // int64 in ref -> int32 here
    const float* eattr  = (const float*)d_in[2];
    const float* W_src  = (const float*)d_in[3];
    const float* b_src  = (const float*)d_in[4];
    const float* W_tgt  = (const float*)d_in[5];
    const float* b_tgt  = (const float*)d_in[6];
    const float* W_edge = (const float*)d_in[7];
    const float* b_edge = (const float*)d_in[8];
    const float* W1     = (const float*)d_in[9];
    const float* b1     = (const float*)d_in[10];
    const float* W2     = (const float*)d_in[11];
    const float* b2     = (const float*)d_in[12];
    const float* W3     = (const float*)d_in[13];
    const float* b3     = (const float*)d_in[14];
    float* out = (float*)d_out;

    const size_t N64 = (size_t)NNODES * 64;

    // workspace layout
    float* xtgt           = (float*)d_ws;                         // N64 f32
    unsigned short* xsrcB = (unsigned short*)(xtgt + N64);        // N64 bf16
    unsigned char* ps8    = (unsigned char*)(xsrcB + N64);        // N64 fp8
    unsigned char* pt8    = ps8 + N64;                            // N64 fp8
    float* attv           = (float*)(pt8 + N64);                  // E f32
    float2* csr           = (float2*)(attv + (size_t)NEDGES);     // E float2
    int* deg              = (int*)(csr + (size_t)NEDGES);         // N
    int* offs             = deg + NNODES;                         // N
    int* cursor           = offs + NNODES;                        // N
    float* Ms             = (float*)(cursor + NNODES);            // 4096
    float* Mt             = Ms + 4096;                            // 4096
    float* w1cp           = Mt + 4096;                            // 512
    float* btot           = w1cp + 512;                           // 64
    int*   psum           = (int*)(btot + 64);                    // 98

    const int NB = (NNODES + 1023) / 1024;   // 98

    egat_precompute<<<1, 256, 0, stream>>>(W1, b1, W_src, b_src, W_tgt, b_tgt,
                                           W_edge, b_edge, Ms, Mt, w1cp, btot);
    egat_zero<<<(NNODES + 255) / 256, 256, 0, stream>>>(deg);
    egat_nodeM<<<640, 256, 0, stream>>>(x, W_src, b_src, W_tgt, b_tgt,
                                        Ms, Mt, btot, xsrcB, xtgt, ps8, pt8);
    egat_edge<<<NEDGES / 256, 256, 0, stream>>>(ei, eattr, ps8, pt8,
                                                w1cp, W2, b2, W3, b3, attv, deg);
    egat_scan1<<<NB, 1024, 0, stream>>>(deg, offs, psum);
    egat_scan2<<<1, 128, 0, stream>>>(psum, NB);
    egat_scan3<<<NB, 1024, 0, stream>>>(offs, psum, cursor);
    egat_scatter<<<NEDGES / 256, 256, 0, stream>>>(ei, attv, cursor, csr);
    egat_gather<<<(NNODES * 64) / 256, 256, 0, stream>>>(csr, offs, cursor,
                                                         xsrcB, xtgt, out);
}